// Round 7
// baseline (627.219 us; speedup 1.0000x reference)
//
#include <hip/hip_runtime.h>
#include <hip/hip_bf16.h>
#include <cstdint>

#define N_SAMP 8192
#define IN_DIM 1024
#define HID    2048
#define NE     4

typedef __attribute__((ext_vector_type(8))) __bf16 bf16x8;
typedef __attribute__((ext_vector_type(4))) float  f32x4;

#define MFMA16 __builtin_amdgcn_mfma_f32_16x16x32_bf16

__device__ __forceinline__ unsigned short f2b(float f) {
    unsigned u = __float_as_uint(f);
    u += 0x7fff + ((u >> 16) & 1);          // RNE, finite inputs only
    return (unsigned short)(u >> 16);
}
__device__ __forceinline__ float b2f(unsigned short s) {
    return __uint_as_float(((unsigned)s) << 16);
}

// async global->LDS, 16B per lane; LDS dest is wave-uniform base (+lane*16 by HW)
__device__ __forceinline__ void gll16(const void* g, void* l) {
    __builtin_amdgcn_global_load_lds(
        (const __attribute__((address_space(1))) void*)g,
        (__attribute__((address_space(3))) void*)l,
        16, 0, 0);
}

// LDS byte swizzle for 128B-row tiles: bits 4-6 ^= row bits 0-2 (byte bits 7-9).
// Involution; keeps 16B alignment; conflict-free ds_read_b128 (verified r6: conflicts=0).
__device__ __forceinline__ int swz(int byte) {
    return byte ^ (((byte >> 7) & 7) << 4);
}

// ---------------- f32 -> bf16 elementwise ----------------
__global__ void conv_bf16(const float* __restrict__ s, unsigned short* __restrict__ d, int n) {
    int i = (blockIdx.x * blockDim.x + threadIdx.x) * 4;
    if (i >= n) return;
    float4 v = *(const float4*)&s[i];
    ushort4 o;
    o.x = f2b(v.x); o.y = f2b(v.y); o.z = f2b(v.z); o.w = f2b(v.w);
    *(ushort4*)&d[i] = o;
}

// ---------------- transpose + convert: src [e][K][M] f32 -> dst [e][M][K] bf16 ----------------
__global__ void transpose_conv(const float* __restrict__ src, unsigned short* __restrict__ dst,
                               int K, int M, size_t srcStride, size_t dstStride) {
    __shared__ float tile[64][65];
    const int e  = blockIdx.z;
    const int k0 = blockIdx.x * 64, m0 = blockIdx.y * 64;
    const int t  = threadIdx.x;
    const int tc = t & 15, tr = t >> 4;
    const float* s = src + (size_t)e * srcStride + (size_t)k0 * M + m0;
    #pragma unroll
    for (int r = tr; r < 64; r += 16) {
        float4 v = *(const float4*)&s[(size_t)r * M + tc * 4];
        tile[r][tc * 4 + 0] = v.x; tile[r][tc * 4 + 1] = v.y;
        tile[r][tc * 4 + 2] = v.z; tile[r][tc * 4 + 3] = v.w;
    }
    __syncthreads();
    unsigned short* d = dst + (size_t)e * dstStride + (size_t)m0 * K + k0;
    #pragma unroll
    for (int r = tr; r < 64; r += 16) {
        ushort4 o;
        o.x = f2b(tile[tc * 4 + 0][r]); o.y = f2b(tile[tc * 4 + 1][r]);
        o.z = f2b(tile[tc * 4 + 2][r]); o.w = f2b(tile[tc * 4 + 3][r]);
        *(ushort4*)&d[(size_t)r * K + tc * 4] = o;
    }
}

// ---------------- router: fp32 logits, softmax, first-max argmax, reg_loss ----------------
__global__ void router_kernel(const float* __restrict__ bb, const int* __restrict__ task,
                              const float* __restrict__ temb, const float* __restrict__ rm,
                              float* __restrict__ gval, int* __restrict__ gidx,
                              float* __restrict__ regout) {
    const int t = threadIdx.x, wave = t >> 6, lane = t & 63;
    const int n = blockIdx.x * 4 + wave;
    const int tk = task[n];
    float a0 = 0.f, a1 = 0.f, a2 = 0.f, a3 = 0.f;
    for (int i = lane; i < IN_DIM + 100; i += 64) {
        float x = (i < IN_DIM) ? bb[(size_t)n * IN_DIM + i] : temb[tk * 100 + (i - IN_DIM)];
        float4 r = *(const float4*)&rm[i * 4];
        a0 += x * r.x; a1 += x * r.y; a2 += x * r.z; a3 += x * r.w;
    }
    #pragma unroll
    for (int o = 32; o; o >>= 1) {
        a0 += __shfl_xor(a0, o); a1 += __shfl_xor(a1, o);
        a2 += __shfl_xor(a2, o); a3 += __shfl_xor(a3, o);
    }
    if (lane == 0) {
        float l[4] = {a0, a1, a2, a3};
        float mx = fmaxf(fmaxf(l[0], l[1]), fmaxf(l[2], l[3]));
        float ex[4], s = 0.f;
        #pragma unroll
        for (int j = 0; j < 4; j++) { ex[j] = expf(l[j] - mx); s += ex[j]; }
        int bi = 0; float bw = ex[0];
        #pragma unroll
        for (int j = 1; j < 4; j++) if (ex[j] > bw) { bw = ex[j]; bi = j; }
        float g = bw / s;
        gval[n] = g;
        gidx[n] = bi;
        regout[n] = -0.0025f * (logf(g + 1e-6f) + 3.0f * logf(1e-6f));
    }
}

// ---------------- per-expert compaction: list_e = {n : idx[n] >= e}; pad to mult 256 --------
__global__ void compact_kernel(const int* __restrict__ gidx, int* __restrict__ list,
                               int* __restrict__ pos, int* __restrict__ cnt) {
    const int e = blockIdx.x;
    const int t = threadIdx.x, lane = t & 63, wave = t >> 6;
    __shared__ int wbase[4];
    __shared__ int running;
    if (t == 0) running = 0;
    __syncthreads();
    int* le = list + (size_t)e * N_SAMP;
    int* pe = pos + (size_t)e * N_SAMP;
    for (int base = 0; base < N_SAMP; base += 256) {
        const int n = base + t;
        const bool f = gidx[n] >= e;
        unsigned long long m = __ballot(f);
        int rank = __popcll(m & ((1ULL << lane) - 1ULL));
        if (lane == 0) wbase[wave] = __popcll(m);
        __syncthreads();
        int wb = 0;
        #pragma unroll
        for (int w = 0; w < 4; w++) if (w < wave) wb += wbase[w];
        int tot = wbase[0] + wbase[1] + wbase[2] + wbase[3];
        int o = running + wb + rank;
        if (f) { le[o] = n; pe[n] = o; }
        __syncthreads();
        if (t == 0) running += tot;
        __syncthreads();
    }
    const int c = running;
    if (t == 0) cnt[e] = c;
    const int padded = (c + 255) & ~255;
    for (int i = c + t; i < padded && i < N_SAMP; i += 256) le[i] = 0;
}

// ================= 256x256 8-phase bf16 MFMA GEMM, multi-expert fused =================
// bid decode: e = bid>>8, mb = bid&7, nb = (bid>>3)&31. Per-expert pointers via strides.
// Fallback (per-expert launch): grid 256 -> e=0, base pointers pre-offset, strides unused.
__global__ __launch_bounds__(512, 2) void gemm256(
    const unsigned short* __restrict__ A, const unsigned short* __restrict__ BT,
    const float* __restrict__ bias, unsigned short* __restrict__ C,
    int K, int M, const int* __restrict__ rowlistBase, const int* __restrict__ cntBase,
    size_t aStride, size_t btStride, size_t cStride, int listStride) {
    extern __shared__ unsigned short lds_[];   // 131072 bytes
    const int bid = blockIdx.x;
    const int e = bid >> 8;
    const int inner = bid & 255;
    const int mb = inner & 7, nb = inner >> 3;
    const int cnt = cntBase[e];
    const int n0 = nb * 256;
    if (n0 >= cnt) return;
    const int m0 = mb * 256;
    const unsigned short* Ae  = A + (size_t)e * aStride;
    const unsigned short* BTe = BT + (size_t)e * btStride;
    const float*          be  = bias + (size_t)e * HID;
    unsigned short*       Ce  = C + (size_t)e * cStride;
    const int* rowlist = listStride ? rowlistBase + (size_t)e * listStride : rowlistBase;

    const int t = threadIdx.x;
    const int w = t >> 6, lane = t & 63;
    const int wm = w >> 2, wn = w & 3;          // wave -> (sample-half, m-quarter)
    const int lrow = lane & 15, kg = lane >> 4;

    // staging geometry: thread covers chunks t and t+512 of each 16KB half-tile;
    // source address pre-swizzled so that swizzled ds_read sees element (r,c).
    int rr[2], cb[2];
    #pragma unroll
    for (int q = 0; q < 2; q++) {
        int P = (t + q * 512) * 16;
        int Ps = swz(P);
        rr[q] = Ps >> 7;                        // row within 128-row half
        cb[q] = Ps & 127;                       // byte within 128B row
    }
    int gA[2][2], gB[2][2];
    #pragma unroll
    for (int h = 0; h < 2; h++)
        #pragma unroll
        for (int q = 0; q < 2; q++) {
            int r = n0 + h * 128 + rr[q];
            gA[h][q] = rowlist ? rowlist[r] : r;
            gB[h][q] = m0 + h * 128 + rr[q];
        }

    auto stageA = [&](int buf, int h, int kt) {
        #pragma unroll
        for (int q = 0; q < 2; q++) {
            const char* src = (const char*)(Ae + (size_t)gA[h][q] * K) + kt * 128 + cb[q];
            gll16(src, &lds_[buf * 32768 + h * 8192 + q * 4096 + w * 512]);
        }
    };
    auto stageB = [&](int buf, int h, int kt) {
        #pragma unroll
        for (int q = 0; q < 2; q++) {
            const char* src = (const char*)(BTe + (size_t)gB[h][q] * K) + kt * 128 + cb[q];
            gll16(src, &lds_[buf * 32768 + 16384 + h * 8192 + q * 4096 + w * 512]);
        }
    };
    auto ldA = [&](int buf, int i, int kk) -> bf16x8 {
        int byte = (i * 16 + lrow) * 128 + (kk * 32 + kg * 8) * 2;
        byte = swz(byte);
        return *(const bf16x8*)&lds_[buf * 32768 + wm * 8192 + (byte >> 1)];
    };
    auto ldB = [&](int buf, int j, int kk) -> bf16x8 {
        int byte = ((wn & 1) * 64 + j * 16 + lrow) * 128 + (kk * 32 + kg * 8) * 2;
        byte = swz(byte);
        return *(const bf16x8*)&lds_[buf * 32768 + 16384 + (wn >> 1) * 8192 + (byte >> 1)];
    };

    f32x4 acc[8][4];
    #pragma unroll
    for (int i = 0; i < 8; i++)
        #pragma unroll
        for (int j = 0; j < 4; j++) acc[i][j] = (f32x4){0.f, 0.f, 0.f, 0.f};

    const int nt = K >> 6;   // >= 3 always here (16 or 32)

    // prologue: tile0 all 4 halves + tile1 {A0,A1,B0}; vmcnt(6) retires tile0 exactly.
    stageA(0, 0, 0); stageA(0, 1, 0); stageB(0, 0, 0); stageB(0, 1, 0);
    stageA(1, 0, 1); stageA(1, 1, 1); stageB(1, 0, 1);
    asm volatile("s_waitcnt vmcnt(6)" ::: "memory");
    __builtin_amdgcn_s_barrier();

    bf16x8 af[8][2], bf[2][2];
    for (int kt = 0; kt < nt; ++kt) {
        const int buf = kt & 1;
        // ---- phase 0: quadrant i0-3 x j0-1 (12 ds_reads); stage B1(t+1) -> buf^1
        #pragma unroll
        for (int i = 0; i < 4; i++) { af[i][0] = ldA(buf, i, 0); af[i][1] = ldA(buf, i, 1); }
        #pragma unroll
        for (int j = 0; j < 2; j++) { bf[j][0] = ldB(buf, j, 0); bf[j][1] = ldB(buf, j, 1); }
        if (kt + 1 < nt) stageB(buf ^ 1, 1, kt + 1);
        __builtin_amdgcn_s_barrier();
        __builtin_amdgcn_s_setprio(1);
        #pragma unroll
        for (int i = 0; i < 4; i++)
            #pragma unroll
            for (int j = 0; j < 2; j++) {
                acc[i][j] = MFMA16(af[i][0], bf[j][0], acc[i][j], 0, 0, 0);
                acc[i][j] = MFMA16(af[i][1], bf[j][1], acc[i][j], 0, 0, 0);
            }
        __builtin_amdgcn_s_setprio(0);
        __builtin_amdgcn_s_barrier();
        // ---- phase 1: i4-7 x j0-1 (8 ds_reads)
        #pragma unroll
        for (int i = 4; i < 8; i++) { af[i][0] = ldA(buf, i, 0); af[i][1] = ldA(buf, i, 1); }
        __builtin_amdgcn_s_barrier();
        __builtin_amdgcn_s_setprio(1);
        #pragma unroll
        for (int i = 4; i < 8; i++)
            #pragma unroll
            for (int j = 0; j < 2; j++) {
                acc[i][j] = MFMA16(af[i][0], bf[j][0], acc[i][j], 0, 0, 0);
                acc[i][j] = MFMA16(af[i][1], bf[j][1], acc[i][j], 0, 0, 0);
            }
        __builtin_amdgcn_s_setprio(0);
        __builtin_amdgcn_s_barrier();
        // ---- phase 2: i0-3 x j2-3 (4 ds_reads); stage A0,A1(t+2) -> same buf (A reads done)
        #pragma unroll
        for (int j = 0; j < 2; j++) { bf[j][0] = ldB(buf, 2 + j, 0); bf[j][1] = ldB(buf, 2 + j, 1); }
        if (kt + 2 < nt) { stageA(buf, 0, kt + 2); stageA(buf, 1, kt + 2); }
        __builtin_amdgcn_s_barrier();
        __builtin_amdgcn_s_setprio(1);
        #pragma unroll
        for (int i = 0; i < 4; i++)
            #pragma unroll
            for (int j = 0; j < 2; j++) {
                acc[i][2 + j] = MFMA16(af[i][0], bf[j][0], acc[i][2 + j], 0, 0, 0);
                acc[i][2 + j] = MFMA16(af[i][1], bf[j][1], acc[i][2 + j], 0, 0, 0);
            }
        __builtin_amdgcn_s_setprio(0);
        __builtin_amdgcn_s_barrier();
        // ---- phase 3: i4-7 x j2-3 (0 ds_reads); stage B0(t+2)
        if (kt + 2 < nt) stageB(buf, 0, kt + 2);
        __builtin_amdgcn_s_barrier();
        __builtin_amdgcn_s_setprio(1);
        #pragma unroll
        for (int i = 4; i < 8; i++)
            #pragma unroll
            for (int j = 0; j < 2; j++) {
                acc[i][2 + j] = MFMA16(af[i][0], bf[j][0], acc[i][2 + j], 0, 0, 0);
                acc[i][2 + j] = MFMA16(af[i][1], bf[j][1], acc[i][2 + j], 0, 0, 0);
            }
        __builtin_amdgcn_s_setprio(0);
        // K-tile boundary: counted vmcnt (3 half-tiles = 6 loads in flight), then barrier
        if (kt < nt - 2) asm volatile("s_waitcnt vmcnt(6)" ::: "memory");
        else             asm volatile("s_waitcnt vmcnt(0)" ::: "memory");
        __builtin_amdgcn_s_barrier();
    }

    // epilogue: C/D layout col=lane&15, row=(lane>>4)*4+q  (m89-verified)
    float bv[4];
    #pragma unroll
    for (int j = 0; j < 4; j++)
        bv[j] = be[m0 + wn * 64 + j * 16 + lrow];
    #pragma unroll
    for (int i = 0; i < 8; i++) {
        const int srow0 = n0 + wm * 128 + i * 16 + kg * 4;
        #pragma unroll
        for (int j = 0; j < 4; j++) {
            const int col = m0 + wn * 64 + j * 16 + lrow;
            #pragma unroll
            for (int q = 0; q < 4; q++) {
                if (srow0 + q < cnt) {
                    float x = acc[i][j][q] + bv[j];
                    Ce[(size_t)(srow0 + q) * M + col] = f2b(fmaxf(x, 0.f));
                }
            }
        }
    }
}

// ---------------- Gram-Schmidt + gather: one wave per sample (compact obf via pos) ------------
__global__ void gs_kernel(const unsigned short* __restrict__ eo, const float* __restrict__ gval,
                          const int* __restrict__ gidx, const int* __restrict__ pos,
                          float* __restrict__ dout) {
    const int t = threadIdx.x, wave = t >> 6, lane = t & 63;
    const int n = blockIdx.x * 4 + wave;
    const int idx = gidx[n];
    const float g = gval[n];

    float v[32], b0[32], b1[32], b2[32];

    auto loadv = [&](float* dst, int e) {
        const size_t row = pos[(size_t)e * N_SAMP + n];
        const unsigned short* p = eo + ((size_t)e * N_SAMP + row) * HID + lane * 8;
        #pragma unroll
        for (int c = 0; c < 4; c++) {
            uint4 u = *(const uint4*)(p + c * 512);
            const unsigned short* us = (const unsigned short*)&u;
            #pragma unroll
            for (int j = 0; j < 8; j++) dst[c * 8 + j] = b2f(us[j]);
        }
    };
    auto wdot = [&](const float* x, const float* y) -> float {
        float s = 0.f;
        #pragma unroll
        for (int k = 0; k < 32; k++) s += x[k] * y[k];
        #pragma unroll
        for (int o = 32; o; o >>= 1) s += __shfl_xor(s, o);
        return s;
    };
    auto storev = [&](const float* b) {
        float* o = dout + (size_t)n * HID + lane * 8;
        #pragma unroll
        for (int c = 0; c < 4; c++) {
            float4 x0, x1;
            x0.x = g * b[c * 8 + 0]; x0.y = g * b[c * 8 + 1];
            x0.z = g * b[c * 8 + 2]; x0.w = g * b[c * 8 + 3];
            x1.x = g * b[c * 8 + 4]; x1.y = g * b[c * 8 + 5];
            x1.z = g * b[c * 8 + 6]; x1.w = g * b[c * 8 + 7];
            *(float4*)(o + c * 512) = x0;
            *(float4*)(o + c * 512 + 4) = x1;
        }
    };

    loadv(v, 0);
    float inv = 1.f / sqrtf(wdot(v, v));
    #pragma unroll
    for (int k = 0; k < 32; k++) b0[k] = v[k] * inv;
    if (idx == 0) { storev(b0); return; }
    loadv(v, 1);
    {
        float cc0 = wdot(v, b0);
        #pragma unroll
        for (int k = 0; k < 32; k++) v[k] -= cc0 * b0[k];
        inv = 1.f / sqrtf(wdot(v, v));
        #pragma unroll
        for (int k = 0; k < 32; k++) b1[k] = v[k] * inv;
    }
    if (idx == 1) { storev(b1); return; }
    loadv(v, 2);
    {
        float cc0 = wdot(v, b0);
        float cc1 = wdot(v, b1);
        #pragma unroll
        for (int k = 0; k < 32; k++) v[k] -= cc0 * b0[k] + cc1 * b1[k];
        inv = 1.f / sqrtf(wdot(v, v));
        #pragma unroll
        for (int k = 0; k < 32; k++) b2[k] = v[k] * inv;
    }
    if (idx == 2) { storev(b2); return; }
    loadv(v, 3);
    {
        float cc0 = wdot(v, b0);
        float cc1 = wdot(v, b1);
        float cc2 = wdot(v, b2);
        #pragma unroll
        for (int k = 0; k < 32; k++) v[k] -= cc0 * b0[k] + cc1 * b1[k] + cc2 * b2[k];
        inv = 1.f / sqrtf(wdot(v, v));
        #pragma unroll
        for (int k = 0; k < 32; k++) v[k] *= inv;
    }
    storev(v);
}

extern "C" void kernel_launch(void* const* d_in, const int* in_sizes, int n_in,
                              void* d_out, int out_size, void* d_ws, size_t ws_size,
                              hipStream_t stream) {
    const float* bb   = (const float*)d_in[0];
    const int*   task = (const int*)d_in[1];
    const float* temb = (const float*)d_in[2];
    const float* rm   = (const float*)d_in[3];
    const float* W1   = (const float*)d_in[4];
    const float* b1   = (const float*)d_in[5];
    const float* W2   = (const float*)d_in[6];
    const float* b2   = (const float*)d_in[7];
    float* out = (float*)d_out;
    char* ws = (char*)d_ws;

    const size_t lds_bytes = 131072;
    const size_t FUSED_NEED = 302317584;   // see fused layout below

    if (ws_size >= FUSED_NEED) {
        // ===== fused path: one dispatch per GEMM stage, all experts =====
        // lifetime-aliased layout:
        //   hbf  @ 0         128 MB  [E][N][HID]      (GEMM1 -> GEMM2)
        //   Abf  @ 128 MB     16 MB                   (conv -> GEMM1, then dead)
        //   W1T  @ 144 MB     16 MB  [E][HID][IN_DIM] (transpose -> GEMM1, then dead)
        //   obf  @ 128 MB    128 MB  [E][N][HID]      (GEMM2 -> gs; overlaps dead Abf+W1T)
        //   W2T  @ 256 MB     32 MB  [E][HID][HID]    (transpose -> GEMM2)
        //   small @ 288 MB   ~320 KB
        unsigned short* hbf  = (unsigned short*)(ws + 0);
        unsigned short* Abf  = (unsigned short*)(ws + 134217728);
        unsigned short* W1T  = (unsigned short*)(ws + 150994944);
        unsigned short* obf  = (unsigned short*)(ws + 134217728);   // overlaps Abf+W1T (dead by GEMM2)
        unsigned short* W2T  = (unsigned short*)(ws + 268435456);
        float*          gv   = (float*)(ws + 301989888);
        int*            gi   = (int*)(ws + 301989888 + 32768);
        int*            list = (int*)(ws + 301989888 + 65536);
        int*            pos  = (int*)(ws + 301989888 + 196608);
        int*            cnt  = (int*)(ws + 301989888 + 327680);

        conv_bf16<<<(N_SAMP * IN_DIM) / 1024, 256, 0, stream>>>(bb, Abf, N_SAMP * IN_DIM);
        router_kernel<<<N_SAMP / 4, 256, 0, stream>>>(bb, task, temb, rm, gv, gi,
                                                      out + (size_t)N_SAMP * HID);
        compact_kernel<<<NE, 256, 0, stream>>>(gi, list, pos, cnt);
        transpose_conv<<<dim3(IN_DIM / 64, HID / 64, NE), 256, 0, stream>>>(
            W1, W1T, IN_DIM, HID, (size_t)IN_DIM * HID, (size_t)IN_DIM * HID);
        transpose_conv<<<dim3(HID / 64, HID / 64, NE), 256, 0, stream>>>(
            W2, W2T, HID, HID, (size_t)HID * HID, (size_t)HID * HID);
        // GEMM1 fused: 4 experts x 256 blocks
        gemm256<<<NE * 256, 512, lds_bytes, stream>>>(
            Abf, W1T, b1, hbf, IN_DIM, HID, list, cnt,
            (size_t)0, (size_t)HID * IN_DIM, (size_t)N_SAMP * HID, N_SAMP);
        // GEMM2 fused
        gemm256<<<NE * 256, 512, lds_bytes, stream>>>(
            hbf, W2T, b2, obf, HID, HID, nullptr, cnt,
            (size_t)N_SAMP * HID, (size_t)HID * HID, (size_t)N_SAMP * HID, 0);
        gs_kernel<<<N_SAMP / 4, 256, 0, stream>>>(obf, gv, gi, pos, out);
    } else {
        // ===== fallback: round-6 per-expert loop, ~197.5 MB =====
        unsigned short* obf  = (unsigned short*)(ws + 0);
        unsigned short* Abf  = (unsigned short*)(ws + 134217728);
        unsigned short* hbf  = (unsigned short*)(ws + 150994944);
        unsigned short* W1T  = (unsigned short*)(ws + 184549376);
        unsigned short* W2T  = (unsigned short*)(ws + 188743680);
        float*          gv   = (float*)(ws + 197132288);
        int*            gi   = (int*)(ws + 197165056);
        int*            list = (int*)(ws + 197197824);
        int*            pos  = (int*)(ws + 197328896);
        int*            cnt  = (int*)(ws + 197459968);

        conv_bf16<<<(N_SAMP * IN_DIM) / 1024, 256, 0, stream>>>(bb, Abf, N_SAMP * IN_DIM);
        router_kernel<<<N_SAMP / 4, 256, 0, stream>>>(bb, task, temb, rm, gv, gi,
                                                      out + (size_t)N_SAMP * HID);
        compact_kernel<<<NE, 256, 0, stream>>>(gi, list, pos, cnt);

        for (int e = 0; e < NE; ++e) {
            transpose_conv<<<dim3(IN_DIM / 64, HID / 64, 1), 256, 0, stream>>>(
                W1 + (size_t)e * IN_DIM * HID, W1T, IN_DIM, HID, 0, 0);
            gemm256<<<256, 512, lds_bytes, stream>>>(
                Abf, W1T, b1 + (size_t)e * HID - (size_t)0 * HID, hbf, IN_DIM, HID,
                list + (size_t)e * N_SAMP, cnt + e, 0, 0, 0, 0);
            transpose_conv<<<dim3(HID / 64, HID / 64, 1), 256, 0, stream>>>(
                W2 + (size_t)e * HID * HID, W2T, HID, HID, 0, 0);
            gemm256<<<256, 512, lds_bytes, stream>>>(
                hbf, W2T, b2 + (size_t)e * HID, obf + (size_t)e * N_SAMP * HID, HID, HID,
                nullptr, cnt + e, 0, 0, 0, 0);
        }
        gs_kernel<<<N_SAMP / 4, 256, 0, stream>>>(obf, gv, gi, pos, out);
    }
}

// Round 8
// 596.304 us; speedup vs baseline: 1.0518x; 1.0518x over previous
//
#include <hip/hip_runtime.h>
#include <hip/hip_bf16.h>
#include <cstdint>

#define N_SAMP 8192
#define IN_DIM 1024
#define HID    2048
#define NE     4

typedef __attribute__((ext_vector_type(8))) __bf16 bf16x8;
typedef __attribute__((ext_vector_type(4))) float  f32x4;

#define MFMA16 __builtin_amdgcn_mfma_f32_16x16x32_bf16

__device__ __forceinline__ unsigned short f2b(float f) {
    unsigned u = __float_as_uint(f);
    u += 0x7fff + ((u >> 16) & 1);          // RNE, finite inputs only
    return (unsigned short)(u >> 16);
}
__device__ __forceinline__ float b2f(unsigned short s) {
    return __uint_as_float(((unsigned)s) << 16);
}

// async global->LDS, 16B per lane; LDS dest is wave-uniform base (+lane*16 by HW)
__device__ __forceinline__ void gll16(const void* g, void* l) {
    __builtin_amdgcn_global_load_lds(
        (const __attribute__((address_space(1))) void*)g,
        (__attribute__((address_space(3))) void*)l,
        16, 0, 0);
}

// LDS byte swizzle for 128B-row tiles: bits 4-6 ^= row bits 0-2 (byte bits 7-9).
// Involution; keeps 16B alignment; conflict-free ds_read_b128 (verified r6: conflicts=0).
__device__ __forceinline__ int swz(int byte) {
    return byte ^ (((byte >> 7) & 7) << 4);
}

// ---------------- f32 -> bf16 elementwise ----------------
__global__ void conv_bf16(const float* __restrict__ s, unsigned short* __restrict__ d, int n) {
    int i = (blockIdx.x * blockDim.x + threadIdx.x) * 4;
    if (i >= n) return;
    float4 v = *(const float4*)&s[i];
    ushort4 o;
    o.x = f2b(v.x); o.y = f2b(v.y); o.z = f2b(v.z); o.w = f2b(v.w);
    *(ushort4*)&d[i] = o;
}

// ---------------- transpose + convert: src [K][M] f32 -> dst [M][K] bf16 ----------------
__global__ void transpose_conv(const float* __restrict__ src, unsigned short* __restrict__ dst,
                               int K, int M) {
    __shared__ float tile[64][65];
    const int k0 = blockIdx.x * 64, m0 = blockIdx.y * 64;
    const int t  = threadIdx.x;
    const int tc = t & 15, tr = t >> 4;
    const float* s = src + (size_t)k0 * M + m0;
    #pragma unroll
    for (int r = tr; r < 64; r += 16) {
        float4 v = *(const float4*)&s[(size_t)r * M + tc * 4];
        tile[r][tc * 4 + 0] = v.x; tile[r][tc * 4 + 1] = v.y;
        tile[r][tc * 4 + 2] = v.z; tile[r][tc * 4 + 3] = v.w;
    }
    __syncthreads();
    unsigned short* d = dst + (size_t)m0 * K + k0;
    #pragma unroll
    for (int r = tr; r < 64; r += 16) {
        ushort4 o;
        o.x = f2b(tile[tc * 4 + 0][r]); o.y = f2b(tile[tc * 4 + 1][r]);
        o.z = f2b(tile[tc * 4 + 2][r]); o.w = f2b(tile[tc * 4 + 3][r]);
        *(ushort4*)&d[(size_t)r * K + tc * 4] = o;
    }
}

// ---------------- router: fp32 logits, softmax, first-max argmax, reg_loss ----------------
__global__ void router_kernel(const float* __restrict__ bb, const int* __restrict__ task,
                              const float* __restrict__ temb, const float* __restrict__ rm,
                              float* __restrict__ gval, int* __restrict__ gidx,
                              float* __restrict__ regout) {
    const int t = threadIdx.x, wave = t >> 6, lane = t & 63;
    const int n = blockIdx.x * 4 + wave;
    const int tk = task[n];
    float a0 = 0.f, a1 = 0.f, a2 = 0.f, a3 = 0.f;
    for (int i = lane; i < IN_DIM + 100; i += 64) {
        float x = (i < IN_DIM) ? bb[(size_t)n * IN_DIM + i] : temb[tk * 100 + (i - IN_DIM)];
        float4 r = *(const float4*)&rm[i * 4];
        a0 += x * r.x; a1 += x * r.y; a2 += x * r.z; a3 += x * r.w;
    }
    #pragma unroll
    for (int o = 32; o; o >>= 1) {
        a0 += __shfl_xor(a0, o); a1 += __shfl_xor(a1, o);
        a2 += __shfl_xor(a2, o); a3 += __shfl_xor(a3, o);
    }
    if (lane == 0) {
        float l[4] = {a0, a1, a2, a3};
        float mx = fmaxf(fmaxf(l[0], l[1]), fmaxf(l[2], l[3]));
        float ex[4], s = 0.f;
        #pragma unroll
        for (int j = 0; j < 4; j++) { ex[j] = expf(l[j] - mx); s += ex[j]; }
        int bi = 0; float bw = ex[0];
        #pragma unroll
        for (int j = 1; j < 4; j++) if (ex[j] > bw) { bw = ex[j]; bi = j; }
        float g = bw / s;
        gval[n] = g;
        gidx[n] = bi;
        regout[n] = -0.0025f * (logf(g + 1e-6f) + 3.0f * logf(1e-6f));
    }
}

// ---------------- per-expert compaction: list_e = {n : idx[n] >= e}; pad to mult 256 --------
__global__ void compact_kernel(const int* __restrict__ gidx, int* __restrict__ list,
                               int* __restrict__ pos, int* __restrict__ cnt) {
    const int e = blockIdx.x;
    const int t = threadIdx.x, lane = t & 63, wave = t >> 6;
    __shared__ int wbase[4];
    __shared__ int running;
    if (t == 0) running = 0;
    __syncthreads();
    int* le = list + (size_t)e * N_SAMP;
    int* pe = pos + (size_t)e * N_SAMP;
    for (int base = 0; base < N_SAMP; base += 256) {
        const int n = base + t;
        const bool f = gidx[n] >= e;
        unsigned long long m = __ballot(f);
        int rank = __popcll(m & ((1ULL << lane) - 1ULL));
        if (lane == 0) wbase[wave] = __popcll(m);
        __syncthreads();
        int wb = 0;
        #pragma unroll
        for (int w = 0; w < 4; w++) if (w < wave) wb += wbase[w];
        int tot = wbase[0] + wbase[1] + wbase[2] + wbase[3];
        int o = running + wb + rank;
        if (f) { le[o] = n; pe[n] = o; }
        __syncthreads();
        if (t == 0) running += tot;
        __syncthreads();
    }
    const int c = running;
    if (t == 0) cnt[e] = c;
    const int padded = (c + 255) & ~255;
    for (int i = c + t; i < padded && i < N_SAMP; i += 256) le[i] = 0;
}

// ================= 256x256 8-phase bf16 MFMA GEMM (KT = compile-time K) =================
// C[i][m] = relu(A[row(i),:] . BT[m,:] + bias[m]), BK=64, 8 waves (2Mx4N), 128KB LDS.
// ds_read addresses = 1 lane-base VGPR + compile-time immediate (swizzle XOR mask is
// lane-constant: row&7 == lrow&7 for all fragments). kt-loop unrolled x2 -> buf literal.
// Phase order: i03xj01, i03xj23, i47xj01, i47xj23 (af[4][2] reused, -32 VGPR liveness).
// Stages: B1(t+1)@ph0, B0(t+2)@ph2, A(t+2)@ph3 -- each after its region's last read+barrier.
// Steady-state 14 loads in flight; boundary vmcnt(6) retires exactly tile t+1's 8 loads.
template<int KT>
__global__ __launch_bounds__(512, 2) void gemm256(
    const unsigned short* __restrict__ A, const unsigned short* __restrict__ BT,
    const float* __restrict__ bias, unsigned short* __restrict__ C,
    int M, const int* __restrict__ rowlist, const int* __restrict__ cntp) {
    constexpr int nt = KT / 64;
    extern __shared__ char lds_[];   // 131072 bytes
    const int cnt = *cntp;
    const int bid = blockIdx.x;
    const int mb = bid & 7, nb = bid >> 3;
    const int n0 = nb * 256;
    if (n0 >= cnt) return;
    const int m0 = mb * 256;
    const int t = threadIdx.x;
    const int w = t >> 6, lane = t & 63;
    const int wm = w >> 2, wn = w & 3;          // wave -> (sample-half, m-quarter)
    const int lrow = lane & 15, kg = lane >> 4;

    // staging geometry: thread covers chunks t and t+512 of each 16KB half-tile;
    // source pre-swizzled so swizzled ds_read sees element (r,c). Base ptrs hoisted.
    int rr[2], cb[2];
    #pragma unroll
    for (int q = 0; q < 2; q++) {
        int Ps = swz((t + q * 512) * 16);
        rr[q] = Ps >> 7;                        // row within 128-row half
        cb[q] = Ps & 127;                       // byte within 128B row
    }
    const char* aS[2][2];
    const char* bS[2][2];
    #pragma unroll
    for (int h = 0; h < 2; h++)
        #pragma unroll
        for (int q = 0; q < 2; q++) {
            int r = n0 + h * 128 + rr[q];
            int ga = rowlist ? rowlist[r] : r;
            aS[h][q] = (const char*)A + (size_t)ga * (KT * 2) + cb[q];
            bS[h][q] = (const char*)BT + (size_t)(m0 + h * 128 + rr[q]) * (KT * 2) + cb[q];
        }

    auto stageA = [&](int buf, int h, int kt) {
        gll16(aS[h][0] + kt * 128, lds_ + buf * 65536 + h * 16384 + w * 1024);
        gll16(aS[h][1] + kt * 128, lds_ + buf * 65536 + h * 16384 + 8192 + w * 1024);
    };
    auto stageB = [&](int buf, int h, int kt) {
        gll16(bS[h][0] + kt * 128, lds_ + buf * 65536 + 32768 + h * 16384 + w * 1024);
        gll16(bS[h][1] + kt * 128, lds_ + buf * 65536 + 32768 + h * 16384 + 8192 + w * 1024);
    };

    // read-side lane bases: addr = base[kk] + buf*65536 + frag*2048 (immediate-foldable)
    const int mask = (lrow & 7) << 4;
    const int c0 = (kg * 16) ^ mask;
    const int c1 = (kg * 16 + 64) ^ mask;
    const char* const pA[2] = { lds_ + wm * 16384 + lrow * 128 + c0,
                                lds_ + wm * 16384 + lrow * 128 + c1 };
    const int browB = (wn & 1) * 64 + lrow;
    const char* const pB[2] = { lds_ + 32768 + (wn >> 1) * 16384 + browB * 128 + c0,
                                lds_ + 32768 + (wn >> 1) * 16384 + browB * 128 + c1 };
    auto ldA = [&](int buf, int i, int kk) -> bf16x8 {
        return *(const bf16x8*)(pA[kk] + buf * 65536 + i * 2048);
    };
    auto ldB = [&](int buf, int j, int kk) -> bf16x8 {
        return *(const bf16x8*)(pB[kk] + buf * 65536 + j * 2048);
    };

    f32x4 acc[8][4];
    #pragma unroll
    for (int i = 0; i < 8; i++)
        #pragma unroll
        for (int j = 0; j < 4; j++) acc[i][j] = (f32x4){0.f, 0.f, 0.f, 0.f};

    // prologue: tile0 all 4 halves + tile1 {A0,A1,B0}; vmcnt(6) retires tile0 exactly.
    stageA(0, 0, 0); stageA(0, 1, 0); stageB(0, 0, 0); stageB(0, 1, 0);
    stageA(1, 0, 1); stageA(1, 1, 1); stageB(1, 0, 1);
    asm volatile("s_waitcnt vmcnt(6)" ::: "memory");
    __builtin_amdgcn_s_barrier();

    bf16x8 af[4][2], bfr[4][2];
    auto tile = [&](int kt, int buf) {
        // ---- phase 0: i0-3 x j0-1 (12 ds_reads); stage B1(t+1) -> buf^1
        #pragma unroll
        for (int i = 0; i < 4; i++) { af[i][0] = ldA(buf, i, 0); af[i][1] = ldA(buf, i, 1); }
        #pragma unroll
        for (int j = 0; j < 2; j++) { bfr[j][0] = ldB(buf, j, 0); bfr[j][1] = ldB(buf, j, 1); }
        if (kt + 1 < nt) stageB(buf ^ 1, 1, kt + 1);
        __builtin_amdgcn_s_barrier();
        __builtin_amdgcn_s_setprio(1);
        #pragma unroll
        for (int i = 0; i < 4; i++)
            #pragma unroll
            for (int j = 0; j < 2; j++) {
                acc[i][j] = MFMA16(af[i][0], bfr[j][0], acc[i][j], 0, 0, 0);
                acc[i][j] = MFMA16(af[i][1], bfr[j][1], acc[i][j], 0, 0, 0);
            }
        __builtin_amdgcn_s_setprio(0);
        __builtin_amdgcn_s_barrier();
        // ---- phase 1: i0-3 x j2-3 (4 ds_reads)
        #pragma unroll
        for (int j = 2; j < 4; j++) { bfr[j][0] = ldB(buf, j, 0); bfr[j][1] = ldB(buf, j, 1); }
        __builtin_amdgcn_s_barrier();
        __builtin_amdgcn_s_setprio(1);
        #pragma unroll
        for (int i = 0; i < 4; i++)
            #pragma unroll
            for (int j = 0; j < 2; j++) {
                acc[i][2 + j] = MFMA16(af[i][0], bfr[2 + j][0], acc[i][2 + j], 0, 0, 0);
                acc[i][2 + j] = MFMA16(af[i][1], bfr[2 + j][1], acc[i][2 + j], 0, 0, 0);
            }
        __builtin_amdgcn_s_setprio(0);
        __builtin_amdgcn_s_barrier();
        // ---- phase 2: i4-7 x j0-1 (8 ds_reads, af reused); stage B0(t+2) -> buf
        #pragma unroll
        for (int i = 0; i < 4; i++) { af[i][0] = ldA(buf, 4 + i, 0); af[i][1] = ldA(buf, 4 + i, 1); }
        if (kt + 2 < nt) stageB(buf, 0, kt + 2);
        __builtin_amdgcn_s_barrier();
        __builtin_amdgcn_s_setprio(1);
        #pragma unroll
        for (int i = 0; i < 4; i++)
            #pragma unroll
            for (int j = 0; j < 2; j++) {
                acc[4 + i][j] = MFMA16(af[i][0], bfr[j][0], acc[4 + i][j], 0, 0, 0);
                acc[4 + i][j] = MFMA16(af[i][1], bfr[j][1], acc[4 + i][j], 0, 0, 0);
            }
        __builtin_amdgcn_s_setprio(0);
        __builtin_amdgcn_s_barrier();
        // ---- phase 3: i4-7 x j2-3 (0 ds_reads); stage A0,A1(t+2) -> buf
        if (kt + 2 < nt) { stageA(buf, 0, kt + 2); stageA(buf, 1, kt + 2); }
        __builtin_amdgcn_s_barrier();
        __builtin_amdgcn_s_setprio(1);
        #pragma unroll
        for (int i = 0; i < 4; i++)
            #pragma unroll
            for (int j = 0; j < 2; j++) {
                acc[4 + i][2 + j] = MFMA16(af[i][0], bfr[2 + j][0], acc[4 + i][2 + j], 0, 0, 0);
                acc[4 + i][2 + j] = MFMA16(af[i][1], bfr[2 + j][1], acc[4 + i][2 + j], 0, 0, 0);
            }
        __builtin_amdgcn_s_setprio(0);
        // K-tile boundary: counted vmcnt (B0(t+2)+A(t+2) = 6 loads stay in flight)
        if (kt < nt - 2) asm volatile("s_waitcnt vmcnt(6)" ::: "memory");
        else             asm volatile("s_waitcnt vmcnt(0)" ::: "memory");
        __builtin_amdgcn_s_barrier();
    };
    for (int kt = 0; kt < nt; kt += 2) { tile(kt, 0); tile(kt + 1, 1); }

    // epilogue: C/D layout col=lane&15, row=(lane>>4)*4+q  (m89-verified)
    float bv[4];
    #pragma unroll
    for (int j = 0; j < 4; j++)
        bv[j] = bias[m0 + wn * 64 + j * 16 + lrow];
    #pragma unroll
    for (int i = 0; i < 8; i++) {
        const int srow0 = n0 + wm * 128 + i * 16 + kg * 4;
        #pragma unroll
        for (int j = 0; j < 4; j++) {
            const int col = m0 + wn * 64 + j * 16 + lrow;
            #pragma unroll
            for (int q = 0; q < 4; q++) {
                if (srow0 + q < cnt) {
                    float x = acc[i][j][q] + bv[j];
                    C[(size_t)(srow0 + q) * M + col] = f2b(fmaxf(x, 0.f));
                }
            }
        }
    }
}

// ---------------- Gram-Schmidt + gather: one wave per sample (compact obf via pos) ------------
__global__ void gs_kernel(const unsigned short* __restrict__ eo, const float* __restrict__ gval,
                          const int* __restrict__ gidx, const int* __restrict__ pos,
                          float* __restrict__ dout) {
    const int t = threadIdx.x, wave = t >> 6, lane = t & 63;
    const int n = blockIdx.x * 4 + wave;
    const int idx = gidx[n];
    const float g = gval[n];

    float v[32], b0[32], b1[32], b2[32];

    auto loadv = [&](float* dst, int e) {
        const size_t row = pos[(size_t)e * N_SAMP + n];
        const unsigned short* p = eo + ((size_t)e * N_SAMP + row) * HID + lane * 8;
        #pragma unroll
        for (int c = 0; c < 4; c++) {
            uint4 u = *(const uint4*)(p + c * 512);
            const unsigned short* us = (const unsigned short*)&u;
            #pragma unroll
            for (int j = 0; j < 8; j++) dst[c * 8 + j] = b2f(us[j]);
        }
    };
    auto wdot = [&](const float* x, const float* y) -> float {
        float s = 0.f;
        #pragma unroll
        for (int k = 0; k < 32; k++) s += x[k] * y[k];
        #pragma unroll
        for (int o = 32; o; o >>= 1) s += __shfl_xor(s, o);
        return s;
    };
    auto storev = [&](const float* b) {
        float* o = dout + (size_t)n * HID + lane * 8;
        #pragma unroll
        for (int c = 0; c < 4; c++) {
            float4 x0, x1;
            x0.x = g * b[c * 8 + 0]; x0.y = g * b[c * 8 + 1];
            x0.z = g * b[c * 8 + 2]; x0.w = g * b[c * 8 + 3];
            x1.x = g * b[c * 8 + 4]; x1.y = g * b[c * 8 + 5];
            x1.z = g * b[c * 8 + 6]; x1.w = g * b[c * 8 + 7];
            *(float4*)(o + c * 512) = x0;
            *(float4*)(o + c * 512 + 4) = x1;
        }
    };

    loadv(v, 0);
    float inv = 1.f / sqrtf(wdot(v, v));
    #pragma unroll
    for (int k = 0; k < 32; k++) b0[k] = v[k] * inv;
    if (idx == 0) { storev(b0); return; }
    loadv(v, 1);
    {
        float cc0 = wdot(v, b0);
        #pragma unroll
        for (int k = 0; k < 32; k++) v[k] -= cc0 * b0[k];
        inv = 1.f / sqrtf(wdot(v, v));
        #pragma unroll
        for (int k = 0; k < 32; k++) b1[k] = v[k] * inv;
    }
    if (idx == 1) { storev(b1); return; }
    loadv(v, 2);
    {
        float cc0 = wdot(v, b0);
        float cc1 = wdot(v, b1);
        #pragma unroll
        for (int k = 0; k < 32; k++) v[k] -= cc0 * b0[k] + cc1 * b1[k];
        inv = 1.f / sqrtf(wdot(v, v));
        #pragma unroll
        for (int k = 0; k < 32; k++) b2[k] = v[k] * inv;
    }
    if (idx == 2) { storev(b2); return; }
    loadv(v, 3);
    {
        float cc0 = wdot(v, b0);
        float cc1 = wdot(v, b1);
        float cc2 = wdot(v, b2);
        #pragma unroll
        for (int k = 0; k < 32; k++) v[k] -= cc0 * b0[k] + cc1 * b1[k] + cc2 * b2[k];
        inv = 1.f / sqrtf(wdot(v, v));
        #pragma unroll
        for (int k = 0; k < 32; k++) v[k] *= inv;
    }
    storev(v);
}

extern "C" void kernel_launch(void* const* d_in, const int* in_sizes, int n_in,
                              void* d_out, int out_size, void* d_ws, size_t ws_size,
                              hipStream_t stream) {
    const float* bb   = (const float*)d_in[0];
    const int*   task = (const int*)d_in[1];
    const float* temb = (const float*)d_in[2];
    const float* rm   = (const float*)d_in[3];
    const float* W1   = (const float*)d_in[4];
    const float* b1   = (const float*)d_in[5];
    const float* W2   = (const float*)d_in[6];
    const float* b2   = (const float*)d_in[7];
    float* out = (float*)d_out;

    // workspace layout (bytes) -- total ~197.5 MB (proven safe; ws_size < 302 MB per r7)
    char* ws = (char*)d_ws;
    unsigned short* obf  = (unsigned short*)(ws + 0);           // 128 MB: [E][N][HID] bf16 (compact rows)
    unsigned short* Abf  = (unsigned short*)(ws + 134217728);   //  16 MB: [N][IN_DIM] bf16
    unsigned short* hbf  = (unsigned short*)(ws + 150994944);   //  32 MB: [N][HID] bf16 (per-expert, compact)
    unsigned short* W1T  = (unsigned short*)(ws + 184549376);   //   4 MB
    unsigned short* W2T  = (unsigned short*)(ws + 188743680);   //   8 MB
    float*          gv   = (float*)(ws + 197132288);            //  32 KB
    int*            gi   = (int*)(ws + 197165056);              //  32 KB
    int*            list = (int*)(ws + 197197824);              // 128 KB: [E][N]
    int*            pos  = (int*)(ws + 197328896);              // 128 KB: [E][N]
    int*            cnt  = (int*)(ws + 197459968);              //  16 B

    conv_bf16<<<(N_SAMP * IN_DIM) / 1024, 256, 0, stream>>>(bb, Abf, N_SAMP * IN_DIM);
    router_kernel<<<N_SAMP / 4, 256, 0, stream>>>(bb, task, temb, rm, gv, gi,
                                                  out + (size_t)N_SAMP * HID);
    compact_kernel<<<NE, 256, 0, stream>>>(gi, list, pos, cnt);

    const size_t lds_bytes = 131072;
    for (int e = 0; e < NE; ++e) {
        transpose_conv<<<dim3(IN_DIM / 64, HID / 64), 256, 0, stream>>>(
            W1 + (size_t)e * IN_DIM * HID, W1T, IN_DIM, HID);
        gemm256<IN_DIM><<<256, 512, lds_bytes, stream>>>(
            Abf, W1T, b1 + (size_t)e * HID, hbf, HID,
            list + (size_t)e * N_SAMP, cnt + e);
        transpose_conv<<<dim3(HID / 64, HID / 64), 256, 0, stream>>>(
            W2 + (size_t)e * HID * HID, W2T, HID, HID);
        gemm256<HID><<<256, 512, lds_bytes, stream>>>(
            hbf, W2T, b2 + (size_t)e * HID, obf + (size_t)e * N_SAMP * HID, HID,
            nullptr, cnt + e);
    }

    gs_kernel<<<N_SAMP / 4, 256, 0, stream>>>(obf, gv, gi, pos, out);
}

// Round 9
// 543.960 us; speedup vs baseline: 1.1531x; 1.0962x over previous
//
#include <hip/hip_runtime.h>
#include <hip/hip_bf16.h>
#include <cstdint>

#define N_SAMP 8192
#define IN_DIM 1024
#define HID    2048
#define NE     4

typedef __attribute__((ext_vector_type(8))) __bf16 bf16x8;
typedef __attribute__((ext_vector_type(4))) float  f32x4;

#define MFMA16 __builtin_amdgcn_mfma_f32_16x16x32_bf16

__device__ __forceinline__ unsigned short f2b(float f) {
    unsigned u = __float_as_uint(f);
    u += 0x7fff + ((u >> 16) & 1);          // RNE, finite inputs only
    return (unsigned short)(u >> 16);
}
__device__ __forceinline__ float b2f(unsigned short s) {
    return __uint_as_float(((unsigned)s) << 16);
}

// async global->LDS, 16B per lane; LDS dest is wave-uniform base (+lane*16 by HW)
__device__ __forceinline__ void gll16(const void* g, void* l) {
    __builtin_amdgcn_global_load_lds(
        (const __attribute__((address_space(1))) void*)g,
        (__attribute__((address_space(3))) void*)l,
        16, 0, 0);
}

// LDS byte swizzle for 128B-row tiles: bits 4-6 ^= row bits 0-2 (byte bits 7-9).
// Involution; keeps 16B alignment; conflict-free ds_read_b128 (verified r6: conflicts=0).
__device__ __forceinline__ int swz(int byte) {
    return byte ^ (((byte >> 7) & 7) << 4);
}

// ---------------- f32 -> bf16 elementwise ----------------
__global__ void conv_bf16(const float* __restrict__ s, unsigned short* __restrict__ d, int n) {
    int i = (blockIdx.x * blockDim.x + threadIdx.x) * 4;
    if (i >= n) return;
    float4 v = *(const float4*)&s[i];
    ushort4 o;
    o.x = f2b(v.x); o.y = f2b(v.y); o.z = f2b(v.z); o.w = f2b(v.w);
    *(ushort4*)&d[i] = o;
}

// ---------------- transpose + convert: src [K][M] f32 -> dst [M][K] bf16 ----------------
__global__ void transpose_conv(const float* __restrict__ src, unsigned short* __restrict__ dst,
                               int K, int M) {
    __shared__ float tile[64][65];
    const int k0 = blockIdx.x * 64, m0 = blockIdx.y * 64;
    const int t  = threadIdx.x;
    const int tc = t & 15, tr = t >> 4;
    const float* s = src + (size_t)k0 * M + m0;
    #pragma unroll
    for (int r = tr; r < 64; r += 16) {
        float4 v = *(const float4*)&s[(size_t)r * M + tc * 4];
        tile[r][tc * 4 + 0] = v.x; tile[r][tc * 4 + 1] = v.y;
        tile[r][tc * 4 + 2] = v.z; tile[r][tc * 4 + 3] = v.w;
    }
    __syncthreads();
    unsigned short* d = dst + (size_t)m0 * K + k0;
    #pragma unroll
    for (int r = tr; r < 64; r += 16) {
        ushort4 o;
        o.x = f2b(tile[tc * 4 + 0][r]); o.y = f2b(tile[tc * 4 + 1][r]);
        o.z = f2b(tile[tc * 4 + 2][r]); o.w = f2b(tile[tc * 4 + 3][r]);
        *(ushort4*)&d[(size_t)r * K + tc * 4] = o;
    }
}

// ---------------- router: fp32 logits, softmax, first-max argmax, reg_loss ----------------
__global__ void router_kernel(const float* __restrict__ bb, const int* __restrict__ task,
                              const float* __restrict__ temb, const float* __restrict__ rm,
                              float* __restrict__ gval, int* __restrict__ gidx,
                              float* __restrict__ regout) {
    const int t = threadIdx.x, wave = t >> 6, lane = t & 63;
    const int n = blockIdx.x * 4 + wave;
    const int tk = task[n];
    float a0 = 0.f, a1 = 0.f, a2 = 0.f, a3 = 0.f;
    for (int i = lane; i < IN_DIM + 100; i += 64) {
        float x = (i < IN_DIM) ? bb[(size_t)n * IN_DIM + i] : temb[tk * 100 + (i - IN_DIM)];
        float4 r = *(const float4*)&rm[i * 4];
        a0 += x * r.x; a1 += x * r.y; a2 += x * r.z; a3 += x * r.w;
    }
    #pragma unroll
    for (int o = 32; o; o >>= 1) {
        a0 += __shfl_xor(a0, o); a1 += __shfl_xor(a1, o);
        a2 += __shfl_xor(a2, o); a3 += __shfl_xor(a3, o);
    }
    if (lane == 0) {
        float l[4] = {a0, a1, a2, a3};
        float mx = fmaxf(fmaxf(l[0], l[1]), fmaxf(l[2], l[3]));
        float ex[4], s = 0.f;
        #pragma unroll
        for (int j = 0; j < 4; j++) { ex[j] = expf(l[j] - mx); s += ex[j]; }
        int bi = 0; float bw = ex[0];
        #pragma unroll
        for (int j = 1; j < 4; j++) if (ex[j] > bw) { bw = ex[j]; bi = j; }
        float g = bw / s;
        gval[n] = g;
        gidx[n] = bi;
        regout[n] = -0.0025f * (logf(g + 1e-6f) + 3.0f * logf(1e-6f));
    }
}

// ---------------- per-expert compaction: list_e = {n : idx[n] >= e}; pad to mult 256 --------
__global__ void compact_kernel(const int* __restrict__ gidx, int* __restrict__ list,
                               int* __restrict__ pos, int* __restrict__ cnt) {
    const int e = blockIdx.x;
    const int t = threadIdx.x, lane = t & 63, wave = t >> 6;
    __shared__ int wbase[4];
    __shared__ int running;
    if (t == 0) running = 0;
    __syncthreads();
    int* le = list + (size_t)e * N_SAMP;
    int* pe = pos + (size_t)e * N_SAMP;
    for (int base = 0; base < N_SAMP; base += 256) {
        const int n = base + t;
        const bool f = gidx[n] >= e;
        unsigned long long m = __ballot(f);
        int rank = __popcll(m & ((1ULL << lane) - 1ULL));
        if (lane == 0) wbase[wave] = __popcll(m);
        __syncthreads();
        int wb = 0;
        #pragma unroll
        for (int w = 0; w < 4; w++) if (w < wave) wb += wbase[w];
        int tot = wbase[0] + wbase[1] + wbase[2] + wbase[3];
        int o = running + wb + rank;
        if (f) { le[o] = n; pe[n] = o; }
        __syncthreads();
        if (t == 0) running += tot;
        __syncthreads();
    }
    const int c = running;
    if (t == 0) cnt[e] = c;
    const int padded = (c + 255) & ~255;
    for (int i = c + t; i < padded && i < N_SAMP; i += 256) le[i] = 0;
}

// ================= 256x256 8-phase bf16 MFMA GEMM core (KT = compile-time K) =================
// Identical to the round-8 proven kernel body; factored as a device function so the
// dual-job wrapper can pack two GEMMs (different K) into one dispatch.
template<int KT>
__device__ __forceinline__ void gemm_core(
    const unsigned short* __restrict__ A, const unsigned short* __restrict__ BT,
    const float* __restrict__ bias, unsigned short* __restrict__ C,
    int M, const int* __restrict__ rowlist, const int* __restrict__ cntp,
    int bid, char* lds_) {
    constexpr int nt = KT / 64;
    const int cnt = *cntp;
    const int mb = bid & 7, nb = bid >> 3;
    const int n0 = nb * 256;
    if (n0 >= cnt) return;
    const int m0 = mb * 256;
    const int t = threadIdx.x;
    const int w = t >> 6, lane = t & 63;
    const int wm = w >> 2, wn = w & 3;          // wave -> (sample-half, m-quarter)
    const int lrow = lane & 15, kg = lane >> 4;

    int rr[2], cb[2];
    #pragma unroll
    for (int q = 0; q < 2; q++) {
        int Ps = swz((t + q * 512) * 16);
        rr[q] = Ps >> 7;
        cb[q] = Ps & 127;
    }
    const char* aS[2][2];
    const char* bS[2][2];
    #pragma unroll
    for (int h = 0; h < 2; h++)
        #pragma unroll
        for (int q = 0; q < 2; q++) {
            int r = n0 + h * 128 + rr[q];
            int ga = rowlist ? rowlist[r] : r;
            aS[h][q] = (const char*)A + (size_t)ga * (KT * 2) + cb[q];
            bS[h][q] = (const char*)BT + (size_t)(m0 + h * 128 + rr[q]) * (KT * 2) + cb[q];
        }

    auto stageA = [&](int buf, int h, int kt) {
        gll16(aS[h][0] + kt * 128, lds_ + buf * 65536 + h * 16384 + w * 1024);
        gll16(aS[h][1] + kt * 128, lds_ + buf * 65536 + h * 16384 + 8192 + w * 1024);
    };
    auto stageB = [&](int buf, int h, int kt) {
        gll16(bS[h][0] + kt * 128, lds_ + buf * 65536 + 32768 + h * 16384 + w * 1024);
        gll16(bS[h][1] + kt * 128, lds_ + buf * 65536 + 32768 + h * 16384 + 8192 + w * 1024);
    };

    const int mask = (lrow & 7) << 4;
    const int c0 = (kg * 16) ^ mask;
    const int c1 = (kg * 16 + 64) ^ mask;
    const char* const pA[2] = { lds_ + wm * 16384 + lrow * 128 + c0,
                                lds_ + wm * 16384 + lrow * 128 + c1 };
    const int browB = (wn & 1) * 64 + lrow;
    const char* const pB[2] = { lds_ + 32768 + (wn >> 1) * 16384 + browB * 128 + c0,
                                lds_ + 32768 + (wn >> 1) * 16384 + browB * 128 + c1 };
    auto ldA = [&](int buf, int i, int kk) -> bf16x8 {
        return *(const bf16x8*)(pA[kk] + buf * 65536 + i * 2048);
    };
    auto ldB = [&](int buf, int j, int kk) -> bf16x8 {
        return *(const bf16x8*)(pB[kk] + buf * 65536 + j * 2048);
    };

    f32x4 acc[8][4];
    #pragma unroll
    for (int i = 0; i < 8; i++)
        #pragma unroll
        for (int j = 0; j < 4; j++) acc[i][j] = (f32x4){0.f, 0.f, 0.f, 0.f};

    stageA(0, 0, 0); stageA(0, 1, 0); stageB(0, 0, 0); stageB(0, 1, 0);
    stageA(1, 0, 1); stageA(1, 1, 1); stageB(1, 0, 1);
    asm volatile("s_waitcnt vmcnt(6)" ::: "memory");
    __builtin_amdgcn_s_barrier();

    bf16x8 af[4][2], bfr[4][2];
    auto tile = [&](int kt, int buf) {
        // ---- phase 0: i0-3 x j0-1 (12 ds_reads); stage B1(t+1) -> buf^1
        #pragma unroll
        for (int i = 0; i < 4; i++) { af[i][0] = ldA(buf, i, 0); af[i][1] = ldA(buf, i, 1); }
        #pragma unroll
        for (int j = 0; j < 2; j++) { bfr[j][0] = ldB(buf, j, 0); bfr[j][1] = ldB(buf, j, 1); }
        if (kt + 1 < nt) stageB(buf ^ 1, 1, kt + 1);
        __builtin_amdgcn_s_barrier();
        __builtin_amdgcn_s_setprio(1);
        #pragma unroll
        for (int i = 0; i < 4; i++)
            #pragma unroll
            for (int j = 0; j < 2; j++) {
                acc[i][j] = MFMA16(af[i][0], bfr[j][0], acc[i][j], 0, 0, 0);
                acc[i][j] = MFMA16(af[i][1], bfr[j][1], acc[i][j], 0, 0, 0);
            }
        __builtin_amdgcn_s_setprio(0);
        __builtin_amdgcn_s_barrier();
        // ---- phase 1: i0-3 x j2-3 (4 ds_reads)
        #pragma unroll
        for (int j = 2; j < 4; j++) { bfr[j][0] = ldB(buf, j, 0); bfr[j][1] = ldB(buf, j, 1); }
        __builtin_amdgcn_s_barrier();
        __builtin_amdgcn_s_setprio(1);
        #pragma unroll
        for (int i = 0; i < 4; i++)
            #pragma unroll
            for (int j = 0; j < 2; j++) {
                acc[i][2 + j] = MFMA16(af[i][0], bfr[2 + j][0], acc[i][2 + j], 0, 0, 0);
                acc[i][2 + j] = MFMA16(af[i][1], bfr[2 + j][1], acc[i][2 + j], 0, 0, 0);
            }
        __builtin_amdgcn_s_setprio(0);
        __builtin_amdgcn_s_barrier();
        // ---- phase 2: i4-7 x j0-1 (8 ds_reads, af reused); stage B0(t+2) -> buf
        #pragma unroll
        for (int i = 0; i < 4; i++) { af[i][0] = ldA(buf, 4 + i, 0); af[i][1] = ldA(buf, 4 + i, 1); }
        if (kt + 2 < nt) stageB(buf, 0, kt + 2);
        __builtin_amdgcn_s_barrier();
        __builtin_amdgcn_s_setprio(1);
        #pragma unroll
        for (int i = 0; i < 4; i++)
            #pragma unroll
            for (int j = 0; j < 2; j++) {
                acc[4 + i][j] = MFMA16(af[i][0], bfr[j][0], acc[4 + i][j], 0, 0, 0);
                acc[4 + i][j] = MFMA16(af[i][1], bfr[j][1], acc[4 + i][j], 0, 0, 0);
            }
        __builtin_amdgcn_s_setprio(0);
        __builtin_amdgcn_s_barrier();
        // ---- phase 3: i4-7 x j2-3 (0 ds_reads); stage A0,A1(t+2) -> buf
        if (kt + 2 < nt) { stageA(buf, 0, kt + 2); stageA(buf, 1, kt + 2); }
        __builtin_amdgcn_s_barrier();
        __builtin_amdgcn_s_setprio(1);
        #pragma unroll
        for (int i = 0; i < 4; i++)
            #pragma unroll
            for (int j = 0; j < 2; j++) {
                acc[4 + i][2 + j] = MFMA16(af[i][0], bfr[2 + j][0], acc[4 + i][2 + j], 0, 0, 0);
                acc[4 + i][2 + j] = MFMA16(af[i][1], bfr[2 + j][1], acc[4 + i][2 + j], 0, 0, 0);
            }
        __builtin_amdgcn_s_setprio(0);
        if (kt < nt - 2) asm volatile("s_waitcnt vmcnt(6)" ::: "memory");
        else             asm volatile("s_waitcnt vmcnt(0)" ::: "memory");
        __builtin_amdgcn_s_barrier();
    };
    for (int kt = 0; kt < nt; kt += 2) { tile(kt, 0); tile(kt + 1, 1); }

    // epilogue: C/D layout col=lane&15, row=(lane>>4)*4+q  (m89-verified)
    float bv[4];
    #pragma unroll
    for (int j = 0; j < 4; j++)
        bv[j] = bias[m0 + wn * 64 + j * 16 + lrow];
    #pragma unroll
    for (int i = 0; i < 8; i++) {
        const int srow0 = n0 + wm * 128 + i * 16 + kg * 4;
        #pragma unroll
        for (int j = 0; j < 4; j++) {
            const int col = m0 + wn * 64 + j * 16 + lrow;
            #pragma unroll
            for (int q = 0; q < 4; q++) {
                if (srow0 + q < cnt) {
                    float x = acc[i][j][q] + bv[j];
                    C[(size_t)(srow0 + q) * M + col] = f2b(fmaxf(x, 0.f));
                }
            }
        }
    }
}

template<int KT>
__global__ __launch_bounds__(512, 2) void gemm256(
    const unsigned short* __restrict__ A, const unsigned short* __restrict__ BT,
    const float* __restrict__ bias, unsigned short* __restrict__ C,
    int M, const int* __restrict__ rowlist, const int* __restrict__ cntp) {
    extern __shared__ char lds_[];
    gemm_core<KT>(A, BT, bias, C, M, rowlist, cntp, blockIdx.x, lds_);
}

// packed dispatch: bids [0,256) = job A (K=2048, GEMM2 of expert e);
//                  bids [256,512) = job B (K=1024, GEMM1 of expert e+1)
__global__ __launch_bounds__(512, 2) void gemm256_dual(
    const unsigned short* __restrict__ A2, const unsigned short* __restrict__ BT2,
    const float* __restrict__ bias2, unsigned short* __restrict__ C2,
    const int* __restrict__ cnt2,
    const unsigned short* __restrict__ A1, const unsigned short* __restrict__ BT1,
    const float* __restrict__ bias1, unsigned short* __restrict__ C1,
    const int* __restrict__ rowlist1, const int* __restrict__ cnt1) {
    extern __shared__ char lds_[];
    const int bid = blockIdx.x;
    if (bid < 256) {
        gemm_core<HID>(A2, BT2, bias2, C2, HID, nullptr, cnt2, bid, lds_);
    } else {
        gemm_core<IN_DIM>(A1, BT1, bias1, C1, HID, rowlist1, cnt1, bid - 256, lds_);
    }
}

// ---------------- Gram-Schmidt + gather: one wave per sample (compact obf via pos) ------------
__global__ void gs_kernel(const unsigned short* __restrict__ eo, const float* __restrict__ gval,
                          const int* __restrict__ gidx, const int* __restrict__ pos,
                          float* __restrict__ dout) {
    const int t = threadIdx.x, wave = t >> 6, lane = t & 63;
    const int n = blockIdx.x * 4 + wave;
    const int idx = gidx[n];
    const float g = gval[n];

    float v[32], b0[32], b1[32], b2[32];

    auto loadv = [&](float* dst, int e) {
        const size_t row = pos[(size_t)e * N_SAMP + n];
        const unsigned short* p = eo + ((size_t)e * N_SAMP + row) * HID + lane * 8;
        #pragma unroll
        for (int c = 0; c < 4; c++) {
            uint4 u = *(const uint4*)(p + c * 512);
            const unsigned short* us = (const unsigned short*)&u;
            #pragma unroll
            for (int j = 0; j < 8; j++) dst[c * 8 + j] = b2f(us[j]);
        }
    };
    auto wdot = [&](const float* x, const float* y) -> float {
        float s = 0.f;
        #pragma unroll
        for (int k = 0; k < 32; k++) s += x[k] * y[k];
        #pragma unroll
        for (int o = 32; o; o >>= 1) s += __shfl_xor(s, o);
        return s;
    };
    auto storev = [&](const float* b) {
        float* o = dout + (size_t)n * HID + lane * 8;
        #pragma unroll
        for (int c = 0; c < 4; c++) {
            float4 x0, x1;
            x0.x = g * b[c * 8 + 0]; x0.y = g * b[c * 8 + 1];
            x0.z = g * b[c * 8 + 2]; x0.w = g * b[c * 8 + 3];
            x1.x = g * b[c * 8 + 4]; x1.y = g * b[c * 8 + 5];
            x1.z = g * b[c * 8 + 6]; x1.w = g * b[c * 8 + 7];
            *(float4*)(o + c * 512) = x0;
            *(float4*)(o + c * 512 + 4) = x1;
        }
    };

    loadv(v, 0);
    float inv = 1.f / sqrtf(wdot(v, v));
    #pragma unroll
    for (int k = 0; k < 32; k++) b0[k] = v[k] * inv;
    if (idx == 0) { storev(b0); return; }
    loadv(v, 1);
    {
        float cc0 = wdot(v, b0);
        #pragma unroll
        for (int k = 0; k < 32; k++) v[k] -= cc0 * b0[k];
        inv = 1.f / sqrtf(wdot(v, v));
        #pragma unroll
        for (int k = 0; k < 32; k++) b1[k] = v[k] * inv;
    }
    if (idx == 1) { storev(b1); return; }
    loadv(v, 2);
    {
        float cc0 = wdot(v, b0);
        float cc1 = wdot(v, b1);
        #pragma unroll
        for (int k = 0; k < 32; k++) v[k] -= cc0 * b0[k] + cc1 * b1[k];
        inv = 1.f / sqrtf(wdot(v, v));
        #pragma unroll
        for (int k = 0; k < 32; k++) b2[k] = v[k] * inv;
    }
    if (idx == 2) { storev(b2); return; }
    loadv(v, 3);
    {
        float cc0 = wdot(v, b0);
        float cc1 = wdot(v, b1);
        float cc2 = wdot(v, b2);
        #pragma unroll
        for (int k = 0; k < 32; k++) v[k] -= cc0 * b0[k] + cc1 * b1[k] + cc2 * b2[k];
        inv = 1.f / sqrtf(wdot(v, v));
        #pragma unroll
        for (int k = 0; k < 32; k++) v[k] *= inv;
    }
    storev(v);
}

extern "C" void kernel_launch(void* const* d_in, const int* in_sizes, int n_in,
                              void* d_out, int out_size, void* d_ws, size_t ws_size,
                              hipStream_t stream) {
    const float* bb   = (const float*)d_in[0];
    const int*   task = (const int*)d_in[1];
    const float* temb = (const float*)d_in[2];
    const float* rm   = (const float*)d_in[3];
    const float* W1   = (const float*)d_in[4];
    const float* b1   = (const float*)d_in[5];
    const float* W2   = (const float*)d_in[6];
    const float* b2   = (const float*)d_in[7];
    float* out = (float*)d_out;

    // workspace layout (bytes) -- total ~197.5 MB (proven safe; ws_size < 302 MB per r7)
    char* ws = (char*)d_ws;
    unsigned short* obf  = (unsigned short*)(ws + 0);           // 128 MB: [E][N][HID] bf16 (compact rows)
    unsigned short* Abf  = (unsigned short*)(ws + 134217728);   //  16 MB: [N][IN_DIM] bf16
    unsigned short* hbfA = (unsigned short*)(ws + 150994944);   //  32 MB: hbf ping (odd experts)
    unsigned short* W1T  = (unsigned short*)(ws + 184549376);   //   4 MB
    unsigned short* W2T  = (unsigned short*)(ws + 188743680);   //   8 MB
    float*          gv   = (float*)(ws + 197132288);            //  32 KB
    int*            gi   = (int*)(ws + 197165056);              //  32 KB
    int*            list = (int*)(ws + 197197824);              // 128 KB: [E][N]
    int*            pos  = (int*)(ws + 197328896);              // 128 KB: [E][N]
    int*            cnt  = (int*)(ws + 197459968);              //  16 B
    // hbf pong (even experts) = obf[3] slot: dead until G2(3) writes it, and
    // G2(3) reads hbfA (odd slot) -> no overlap. Verified against dispatch order.
    unsigned short* hbfB = obf + (size_t)3 * N_SAMP * HID;
    auto hbf = [&](int e) { return (e & 1) ? hbfA : hbfB; };

    conv_bf16<<<(N_SAMP * IN_DIM) / 1024, 256, 0, stream>>>(bb, Abf, N_SAMP * IN_DIM);
    router_kernel<<<N_SAMP / 4, 256, 0, stream>>>(bb, task, temb, rm, gv, gi,
                                                  out + (size_t)N_SAMP * HID);
    compact_kernel<<<NE, 256, 0, stream>>>(gi, list, pos, cnt);

    const size_t lds_bytes = 131072;

    // G1(0) standalone
    transpose_conv<<<dim3(IN_DIM / 64, HID / 64), 256, 0, stream>>>(W1, W1T, IN_DIM, HID);
    gemm256<IN_DIM><<<256, 512, lds_bytes, stream>>>(
        Abf, W1T, b1, hbf(0), HID, list, cnt);

    // packed: [G2(e) | G1(e+1)] for e = 0,1,2
    for (int e = 0; e < 3; ++e) {
        transpose_conv<<<dim3(HID / 64, HID / 64), 256, 0, stream>>>(
            W2 + (size_t)e * HID * HID, W2T, HID, HID);
        transpose_conv<<<dim3(IN_DIM / 64, HID / 64), 256, 0, stream>>>(
            W1 + (size_t)(e + 1) * IN_DIM * HID, W1T, IN_DIM, HID);
        gemm256_dual<<<512, 512, lds_bytes, stream>>>(
            hbf(e), W2T, b2 + (size_t)e * HID, obf + (size_t)e * N_SAMP * HID, cnt + e,
            Abf, W1T, b1 + (size_t)(e + 1) * HID, hbf(e + 1),
            list + (size_t)(e + 1) * N_SAMP, cnt + e + 1);
    }

    // G2(3) standalone (reads hbfA, writes obf[3] = hbfB slot, which is dead)
    transpose_conv<<<dim3(HID / 64, HID / 64), 256, 0, stream>>>(
        W2 + (size_t)3 * HID * HID, W2T, HID, HID);
    gemm256<HID><<<256, 512, lds_bytes, stream>>>(
        hbf(3), W2T, b2 + (size_t)3 * HID, obf + (size_t)3 * N_SAMP * HID, HID,
        nullptr, cnt + 3);

    gs_kernel<<<N_SAMP / 4, 256, 0, stream>>>(obf, gv, gi, pos, out);
}

// Round 10
// 497.781 us; speedup vs baseline: 1.2600x; 1.0928x over previous
//
#include <hip/hip_runtime.h>
#include <hip/hip_bf16.h>
#include <cstdint>

#define N_SAMP 8192
#define IN_DIM 1024
#define HID    2048
#define NE     4

typedef __attribute__((ext_vector_type(8))) __bf16 bf16x8;
typedef __attribute__((ext_vector_type(4))) float  f32x4;

#define MFMA16 __builtin_amdgcn_mfma_f32_16x16x32_bf16

__device__ __forceinline__ unsigned short f2b(float f) {
    unsigned u = __float_as_uint(f);
    u += 0x7fff + ((u >> 16) & 1);          // RNE, finite inputs only
    return (unsigned short)(u >> 16);
}
__device__ __forceinline__ float b2f(unsigned short s) {
    return __uint_as_float(((unsigned)s) << 16);
}

// async global->LDS, 16B per lane; LDS dest is wave-uniform base (+lane*16 by HW)
__device__ __forceinline__ void gll16(const void* g, void* l) {
    __builtin_amdgcn_global_load_lds(
        (const __attribute__((address_space(1))) void*)g,
        (__attribute__((address_space(3))) void*)l,
        16, 0, 0);
}

// LDS byte swizzle for 128B-row tiles: bits 4-6 ^= row bits 0-2 (byte bits 7-9).
// Involution; keeps 16B alignment; conflict-free ds_read_b128 (verified r6: conflicts=0).
__device__ __forceinline__ int swz(int byte) {
    return byte ^ (((byte >> 7) & 7) << 4);
}

// ---------------- f32 -> bf16 elementwise ----------------
__global__ void conv_bf16(const float* __restrict__ s, unsigned short* __restrict__ d, int n) {
    int i = (blockIdx.x * blockDim.x + threadIdx.x) * 4;
    if (i >= n) return;
    float4 v = *(const float4*)&s[i];
    ushort4 o;
    o.x = f2b(v.x); o.y = f2b(v.y); o.z = f2b(v.z); o.w = f2b(v.w);
    *(ushort4*)&d[i] = o;
}

// ---------------- transpose + convert: src [K][M] f32 -> dst [M][K] bf16 ----------------
__global__ void transpose_conv(const float* __restrict__ src, unsigned short* __restrict__ dst,
                               int K, int M) {
    __shared__ float tile[64][65];
    const int k0 = blockIdx.x * 64, m0 = blockIdx.y * 64;
    const int t  = threadIdx.x;
    const int tc = t & 15, tr = t >> 4;
    const float* s = src + (size_t)k0 * M + m0;
    #pragma unroll
    for (int r = tr; r < 64; r += 16) {
        float4 v = *(const float4*)&s[(size_t)r * M + tc * 4];
        tile[r][tc * 4 + 0] = v.x; tile[r][tc * 4 + 1] = v.y;
        tile[r][tc * 4 + 2] = v.z; tile[r][tc * 4 + 3] = v.w;
    }
    __syncthreads();
    unsigned short* d = dst + (size_t)m0 * K + k0;
    #pragma unroll
    for (int r = tr; r < 64; r += 16) {
        ushort4 o;
        o.x = f2b(tile[tc * 4 + 0][r]); o.y = f2b(tile[tc * 4 + 1][r]);
        o.z = f2b(tile[tc * 4 + 2][r]); o.w = f2b(tile[tc * 4 + 3][r]);
        *(ushort4*)&d[(size_t)r * K + tc * 4] = o;
    }
}

// ---------------- router: fp32 logits, softmax, first-max argmax, reg_loss ----------------
__global__ void router_kernel(const float* __restrict__ bb, const int* __restrict__ task,
                              const float* __restrict__ temb, const float* __restrict__ rm,
                              float* __restrict__ gval, int* __restrict__ gidx,
                              float* __restrict__ regout) {
    const int t = threadIdx.x, wave = t >> 6, lane = t & 63;
    const int n = blockIdx.x * 4 + wave;
    const int tk = task[n];
    float a0 = 0.f, a1 = 0.f, a2 = 0.f, a3 = 0.f;
    for (int i = lane; i < IN_DIM + 100; i += 64) {
        float x = (i < IN_DIM) ? bb[(size_t)n * IN_DIM + i] : temb[tk * 100 + (i - IN_DIM)];
        float4 r = *(const float4*)&rm[i * 4];
        a0 += x * r.x; a1 += x * r.y; a2 += x * r.z; a3 += x * r.w;
    }
    #pragma unroll
    for (int o = 32; o; o >>= 1) {
        a0 += __shfl_xor(a0, o); a1 += __shfl_xor(a1, o);
        a2 += __shfl_xor(a2, o); a3 += __shfl_xor(a3, o);
    }
    if (lane == 0) {
        float l[4] = {a0, a1, a2, a3};
        float mx = fmaxf(fmaxf(l[0], l[1]), fmaxf(l[2], l[3]));
        float ex[4], s = 0.f;
        #pragma unroll
        for (int j = 0; j < 4; j++) { ex[j] = expf(l[j] - mx); s += ex[j]; }
        int bi = 0; float bw = ex[0];
        #pragma unroll
        for (int j = 1; j < 4; j++) if (ex[j] > bw) { bw = ex[j]; bi = j; }
        float g = bw / s;
        gval[n] = g;
        gidx[n] = bi;
        regout[n] = -0.0025f * (logf(g + 1e-6f) + 3.0f * logf(1e-6f));
    }
}

// ---------------- per-expert compaction: list_e = {n : idx[n] >= e}; pad to mult 256 --------
__global__ void compact_kernel(const int* __restrict__ gidx, int* __restrict__ list,
                               int* __restrict__ pos, int* __restrict__ cnt) {
    const int e = blockIdx.x;
    const int t = threadIdx.x, lane = t & 63, wave = t >> 6;
    __shared__ int wbase[4];
    __shared__ int running;
    if (t == 0) running = 0;
    __syncthreads();
    int* le = list + (size_t)e * N_SAMP;
    int* pe = pos + (size_t)e * N_SAMP;
    for (int base = 0; base < N_SAMP; base += 256) {
        const int n = base + t;
        const bool f = gidx[n] >= e;
        unsigned long long m = __ballot(f);
        int rank = __popcll(m & ((1ULL << lane) - 1ULL));
        if (lane == 0) wbase[wave] = __popcll(m);
        __syncthreads();
        int wb = 0;
        #pragma unroll
        for (int w = 0; w < 4; w++) if (w < wave) wb += wbase[w];
        int tot = wbase[0] + wbase[1] + wbase[2] + wbase[3];
        int o = running + wb + rank;
        if (f) { le[o] = n; pe[n] = o; }
        __syncthreads();
        if (t == 0) running += tot;
        __syncthreads();
    }
    const int c = running;
    if (t == 0) cnt[e] = c;
    const int padded = (c + 255) & ~255;
    for (int i = c + t; i < padded && i < N_SAMP; i += 256) le[i] = 0;
}

// ================= 256x256 8-phase bf16 MFMA GEMM core (KT = compile-time K) =================
template<int KT>
__device__ __forceinline__ void gemm_core(
    const unsigned short* __restrict__ A, const unsigned short* __restrict__ BT,
    const float* __restrict__ bias, unsigned short* __restrict__ C,
    int M, const int* __restrict__ rowlist, const int* __restrict__ cntp,
    int bid, char* lds_) {
    constexpr int nt = KT / 64;
    const int cnt = *cntp;
    const int mb = bid & 7, nb = bid >> 3;
    const int n0 = nb * 256;
    if (n0 >= cnt) return;
    const int m0 = mb * 256;
    const int t = threadIdx.x;
    const int w = t >> 6, lane = t & 63;
    const int wm = w >> 2, wn = w & 3;          // wave -> (sample-half, m-quarter)
    const int lrow = lane & 15, kg = lane >> 4;

    int rr[2], cb[2];
    #pragma unroll
    for (int q = 0; q < 2; q++) {
        int Ps = swz((t + q * 512) * 16);
        rr[q] = Ps >> 7;
        cb[q] = Ps & 127;
    }
    const char* aS[2][2];
    const char* bS[2][2];
    #pragma unroll
    for (int h = 0; h < 2; h++)
        #pragma unroll
        for (int q = 0; q < 2; q++) {
            int r = n0 + h * 128 + rr[q];
            int ga = rowlist ? rowlist[r] : r;
            aS[h][q] = (const char*)A + (size_t)ga * (KT * 2) + cb[q];
            bS[h][q] = (const char*)BT + (size_t)(m0 + h * 128 + rr[q]) * (KT * 2) + cb[q];
        }

    auto stageA = [&](int buf, int h, int kt) {
        gll16(aS[h][0] + kt * 128, lds_ + buf * 65536 + h * 16384 + w * 1024);
        gll16(aS[h][1] + kt * 128, lds_ + buf * 65536 + h * 16384 + 8192 + w * 1024);
    };
    auto stageB = [&](int buf, int h, int kt) {
        gll16(bS[h][0] + kt * 128, lds_ + buf * 65536 + 32768 + h * 16384 + w * 1024);
        gll16(bS[h][1] + kt * 128, lds_ + buf * 65536 + 32768 + h * 16384 + 8192 + w * 1024);
    };

    const int mask = (lrow & 7) << 4;
    const int c0 = (kg * 16) ^ mask;
    const int c1 = (kg * 16 + 64) ^ mask;
    const char* const pA[2] = { lds_ + wm * 16384 + lrow * 128 + c0,
                                lds_ + wm * 16384 + lrow * 128 + c1 };
    const int browB = (wn & 1) * 64 + lrow;
    const char* const pB[2] = { lds_ + 32768 + (wn >> 1) * 16384 + browB * 128 + c0,
                                lds_ + 32768 + (wn >> 1) * 16384 + browB * 128 + c1 };
    auto ldA = [&](int buf, int i, int kk) -> bf16x8 {
        return *(const bf16x8*)(pA[kk] + buf * 65536 + i * 2048);
    };
    auto ldB = [&](int buf, int j, int kk) -> bf16x8 {
        return *(const bf16x8*)(pB[kk] + buf * 65536 + j * 2048);
    };

    f32x4 acc[8][4];
    #pragma unroll
    for (int i = 0; i < 8; i++)
        #pragma unroll
        for (int j = 0; j < 4; j++) acc[i][j] = (f32x4){0.f, 0.f, 0.f, 0.f};

    stageA(0, 0, 0); stageA(0, 1, 0); stageB(0, 0, 0); stageB(0, 1, 0);
    stageA(1, 0, 1); stageA(1, 1, 1); stageB(1, 0, 1);
    asm volatile("s_waitcnt vmcnt(6)" ::: "memory");
    __builtin_amdgcn_s_barrier();

    bf16x8 af[4][2], bfr[4][2];
    auto tile = [&](int kt, int buf) {
        // ---- phase 0: i0-3 x j0-1 (12 ds_reads); stage B1(t+1) -> buf^1
        #pragma unroll
        for (int i = 0; i < 4; i++) { af[i][0] = ldA(buf, i, 0); af[i][1] = ldA(buf, i, 1); }
        #pragma unroll
        for (int j = 0; j < 2; j++) { bfr[j][0] = ldB(buf, j, 0); bfr[j][1] = ldB(buf, j, 1); }
        if (kt + 1 < nt) stageB(buf ^ 1, 1, kt + 1);
        __builtin_amdgcn_s_barrier();
        __builtin_amdgcn_s_setprio(1);
        #pragma unroll
        for (int i = 0; i < 4; i++)
            #pragma unroll
            for (int j = 0; j < 2; j++) {
                acc[i][j] = MFMA16(af[i][0], bfr[j][0], acc[i][j], 0, 0, 0);
                acc[i][j] = MFMA16(af[i][1], bfr[j][1], acc[i][j], 0, 0, 0);
            }
        __builtin_amdgcn_s_setprio(0);
        __builtin_amdgcn_s_barrier();
        // ---- phase 1: i0-3 x j2-3 (4 ds_reads)
        #pragma unroll
        for (int j = 2; j < 4; j++) { bfr[j][0] = ldB(buf, j, 0); bfr[j][1] = ldB(buf, j, 1); }
        __builtin_amdgcn_s_barrier();
        __builtin_amdgcn_s_setprio(1);
        #pragma unroll
        for (int i = 0; i < 4; i++)
            #pragma unroll
            for (int j = 0; j < 2; j++) {
                acc[i][2 + j] = MFMA16(af[i][0], bfr[2 + j][0], acc[i][2 + j], 0, 0, 0);
                acc[i][2 + j] = MFMA16(af[i][1], bfr[2 + j][1], acc[i][2 + j], 0, 0, 0);
            }
        __builtin_amdgcn_s_setprio(0);
        __builtin_amdgcn_s_barrier();
        // ---- phase 2: i4-7 x j0-1 (8 ds_reads, af reused); stage B0(t+2) -> buf
        #pragma unroll
        for (int i = 0; i < 4; i++) { af[i][0] = ldA(buf, 4 + i, 0); af[i][1] = ldA(buf, 4 + i, 1); }
        if (kt + 2 < nt) stageB(buf, 0, kt + 2);
        __builtin_amdgcn_s_barrier();
        __builtin_amdgcn_s_setprio(1);
        #pragma unroll
        for (int i = 0; i < 4; i++)
            #pragma unroll
            for (int j = 0; j < 2; j++) {
                acc[4 + i][j] = MFMA16(af[i][0], bfr[j][0], acc[4 + i][j], 0, 0, 0);
                acc[4 + i][j] = MFMA16(af[i][1], bfr[j][1], acc[4 + i][j], 0, 0, 0);
            }
        __builtin_amdgcn_s_setprio(0);
        __builtin_amdgcn_s_barrier();
        // ---- phase 3: i4-7 x j2-3 (0 ds_reads); stage A0,A1(t+2) -> buf
        if (kt + 2 < nt) { stageA(buf, 0, kt + 2); stageA(buf, 1, kt + 2); }
        __builtin_amdgcn_s_barrier();
        __builtin_amdgcn_s_setprio(1);
        #pragma unroll
        for (int i = 0; i < 4; i++)
            #pragma unroll
            for (int j = 0; j < 2; j++) {
                acc[4 + i][2 + j] = MFMA16(af[i][0], bfr[2 + j][0], acc[4 + i][2 + j], 0, 0, 0);
                acc[4 + i][2 + j] = MFMA16(af[i][1], bfr[2 + j][1], acc[4 + i][2 + j], 0, 0, 0);
            }
        __builtin_amdgcn_s_setprio(0);
        if (kt < nt - 2) asm volatile("s_waitcnt vmcnt(6)" ::: "memory");
        else             asm volatile("s_waitcnt vmcnt(0)" ::: "memory");
        __builtin_amdgcn_s_barrier();
    };
    for (int kt = 0; kt < nt; kt += 2) { tile(kt, 0); tile(kt + 1, 1); }

    // epilogue: C/D layout col=lane&15, row=(lane>>4)*4+q  (m89-verified)
    float bv[4];
    #pragma unroll
    for (int j = 0; j < 4; j++)
        bv[j] = bias[m0 + wn * 64 + j * 16 + lrow];
    #pragma unroll
    for (int i = 0; i < 8; i++) {
        const int srow0 = n0 + wm * 128 + i * 16 + kg * 4;
        #pragma unroll
        for (int j = 0; j < 4; j++) {
            const int col = m0 + wn * 64 + j * 16 + lrow;
            #pragma unroll
            for (int q = 0; q < 4; q++) {
                if (srow0 + q < cnt) {
                    float x = acc[i][j][q] + bv[j];
                    C[(size_t)(srow0 + q) * M + col] = f2b(fmaxf(x, 0.f));
                }
            }
        }
    }
}

template<int KT>
__global__ __launch_bounds__(512, 2) void gemm256(
    const unsigned short* __restrict__ A, const unsigned short* __restrict__ BT,
    const float* __restrict__ bias, unsigned short* __restrict__ C,
    int M, const int* __restrict__ rowlist, const int* __restrict__ cntp) {
    extern __shared__ char lds_[];
    gemm_core<KT>(A, BT, bias, C, M, rowlist, cntp, blockIdx.x, lds_);
}

// packed: bids [0,256) = G2 (K=HID);  bids [256,512) = G1 (K=IN_DIM)
__global__ __launch_bounds__(512, 2) void gemm256_dual(
    const unsigned short* __restrict__ A2, const unsigned short* __restrict__ BT2,
    const float* __restrict__ bias2, unsigned short* __restrict__ C2,
    const int* __restrict__ cnt2,
    const unsigned short* __restrict__ A1, const unsigned short* __restrict__ BT1,
    const float* __restrict__ bias1, unsigned short* __restrict__ C1,
    const int* __restrict__ rowlist1, const int* __restrict__ cnt1) {
    extern __shared__ char lds_[];
    const int bid = blockIdx.x;
    if (bid < 256) {
        gemm_core<HID>(A2, BT2, bias2, C2, HID, nullptr, cnt2, bid, lds_);
    } else {
        gemm_core<IN_DIM>(A1, BT1, bias1, C1, HID, rowlist1, cnt1, bid - 256, lds_);
    }
}

// packed: two G1 jobs (both K=IN_DIM, shared A)
__global__ __launch_bounds__(512, 2) void gemm256_dual_g1g1(
    const unsigned short* __restrict__ A,
    const unsigned short* __restrict__ BTa, const float* __restrict__ biasa,
    unsigned short* __restrict__ Ca, const int* __restrict__ rla, const int* __restrict__ cnta,
    const unsigned short* __restrict__ BTb, const float* __restrict__ biasb,
    unsigned short* __restrict__ Cb, const int* __restrict__ rlb, const int* __restrict__ cntb) {
    extern __shared__ char lds_[];
    const int bid = blockIdx.x;
    if (bid < 256) {
        gemm_core<IN_DIM>(A, BTa, biasa, Ca, HID, rla, cnta, bid, lds_);
    } else {
        gemm_core<IN_DIM>(A, BTb, biasb, Cb, HID, rlb, cntb, bid - 256, lds_);
    }
}

// packed: two G2 jobs (both K=HID)
__global__ __launch_bounds__(512, 2) void gemm256_dual_g2g2(
    const unsigned short* __restrict__ Aa, const unsigned short* __restrict__ BTa,
    const float* __restrict__ biasa, unsigned short* __restrict__ Ca, const int* __restrict__ cnta,
    const unsigned short* __restrict__ Ab, const unsigned short* __restrict__ BTb,
    const float* __restrict__ biasb, unsigned short* __restrict__ Cb, const int* __restrict__ cntb) {
    extern __shared__ char lds_[];
    const int bid = blockIdx.x;
    if (bid < 256) {
        gemm_core<HID>(Aa, BTa, biasa, Ca, HID, nullptr, cnta, bid, lds_);
    } else {
        gemm_core<HID>(Ab, BTb, biasb, Cb, HID, nullptr, cntb, bid - 256, lds_);
    }
}

// ---------------- Gram-Schmidt + gather: one wave per sample (compact obf via pos) ------------
__global__ void gs_kernel(const unsigned short* __restrict__ eo, const float* __restrict__ gval,
                          const int* __restrict__ gidx, const int* __restrict__ pos,
                          float* __restrict__ dout) {
    const int t = threadIdx.x, wave = t >> 6, lane = t & 63;
    const int n = blockIdx.x * 4 + wave;
    const int idx = gidx[n];
    const float g = gval[n];

    float v[32], b0[32], b1[32], b2[32];

    auto loadv = [&](float* dst, int e) {
        const size_t row = pos[(size_t)e * N_SAMP + n];
        const unsigned short* p = eo + ((size_t)e * N_SAMP + row) * HID + lane * 8;
        #pragma unroll
        for (int c = 0; c < 4; c++) {
            uint4 u = *(const uint4*)(p + c * 512);
            const unsigned short* us = (const unsigned short*)&u;
            #pragma unroll
            for (int j = 0; j < 8; j++) dst[c * 8 + j] = b2f(us[j]);
        }
    };
    auto wdot = [&](const float* x, const float* y) -> float {
        float s = 0.f;
        #pragma unroll
        for (int k = 0; k < 32; k++) s += x[k] * y[k];
        #pragma unroll
        for (int o = 32; o; o >>= 1) s += __shfl_xor(s, o);
        return s;
    };
    auto storev = [&](const float* b) {
        float* o = dout + (size_t)n * HID + lane * 8;
        #pragma unroll
        for (int c = 0; c < 4; c++) {
            float4 x0, x1;
            x0.x = g * b[c * 8 + 0]; x0.y = g * b[c * 8 + 1];
            x0.z = g * b[c * 8 + 2]; x0.w = g * b[c * 8 + 3];
            x1.x = g * b[c * 8 + 4]; x1.y = g * b[c * 8 + 5];
            x1.z = g * b[c * 8 + 6]; x1.w = g * b[c * 8 + 7];
            *(float4*)(o + c * 512) = x0;
            *(float4*)(o + c * 512 + 4) = x1;
        }
    };

    loadv(v, 0);
    float inv = 1.f / sqrtf(wdot(v, v));
    #pragma unroll
    for (int k = 0; k < 32; k++) b0[k] = v[k] * inv;
    if (idx == 0) { storev(b0); return; }
    loadv(v, 1);
    {
        float cc0 = wdot(v, b0);
        #pragma unroll
        for (int k = 0; k < 32; k++) v[k] -= cc0 * b0[k];
        inv = 1.f / sqrtf(wdot(v, v));
        #pragma unroll
        for (int k = 0; k < 32; k++) b1[k] = v[k] * inv;
    }
    if (idx == 1) { storev(b1); return; }
    loadv(v, 2);
    {
        float cc0 = wdot(v, b0);
        float cc1 = wdot(v, b1);
        #pragma unroll
        for (int k = 0; k < 32; k++) v[k] -= cc0 * b0[k] + cc1 * b1[k];
        inv = 1.f / sqrtf(wdot(v, v));
        #pragma unroll
        for (int k = 0; k < 32; k++) b2[k] = v[k] * inv;
    }
    if (idx == 2) { storev(b2); return; }
    loadv(v, 3);
    {
        float cc0 = wdot(v, b0);
        float cc1 = wdot(v, b1);
        float cc2 = wdot(v, b2);
        #pragma unroll
        for (int k = 0; k < 32; k++) v[k] -= cc0 * b0[k] + cc1 * b1[k] + cc2 * b2[k];
        inv = 1.f / sqrtf(wdot(v, v));
        #pragma unroll
        for (int k = 0; k < 32; k++) v[k] *= inv;
    }
    storev(v);
}

extern "C" void kernel_launch(void* const* d_in, const int* in_sizes, int n_in,
                              void* d_out, int out_size, void* d_ws, size_t ws_size,
                              hipStream_t stream) {
    const float* bb   = (const float*)d_in[0];
    const int*   task = (const int*)d_in[1];
    const float* temb = (const float*)d_in[2];
    const float* rm   = (const float*)d_in[3];
    const float* W1   = (const float*)d_in[4];
    const float* b1   = (const float*)d_in[5];
    const float* W2   = (const float*)d_in[6];
    const float* b2   = (const float*)d_in[7];
    float* out = (float*)d_out;
    char* ws = (char*)d_ws;

    const size_t lds_bytes = 131072;
    const size_t PLAN_A_NEED = 243597376;

    if (ws_size >= PLAN_A_NEED) {
        // ===== Plan A: fully packed GEMM schedule, ~243.6 MB =====
        // D0:[G1(0)|G1(1)]  D1:[G2(0)|G1(2)]  D2:[G2(1)|G1(3)]  D3:[G2(2)|G2(3)]
        // h0 lives in obf[1] slot (read D1 < write D2), h1 in obf[2] slot (read D2 < write D3),
        // h2/h3 dedicated (their D3 reads share the dispatch with obf[2]/[3] writes).
        unsigned short* obf  = (unsigned short*)(ws + 0);           // 128 MB [E][N][HID]
        unsigned short* h0   = (unsigned short*)(ws + 33554432);    // = obf[1] slot
        unsigned short* h1   = (unsigned short*)(ws + 67108864);    // = obf[2] slot
        unsigned short* Abf  = (unsigned short*)(ws + 134217728);   // 16 MB
        unsigned short* h2   = (unsigned short*)(ws + 150994944);   // 32 MB
        unsigned short* h3   = (unsigned short*)(ws + 184549376);   // 32 MB
        unsigned short* W1Ta = (unsigned short*)(ws + 218103808);   // 4 MB
        unsigned short* W1Tb = (unsigned short*)(ws + 222298112);   // 4 MB
        unsigned short* W2Ta = (unsigned short*)(ws + 226492416);   // 8 MB
        unsigned short* W2Tb = (unsigned short*)(ws + 234881024);   // 8 MB
        float*          gv   = (float*)(ws + 243269632);
        int*            gi   = (int*)(ws + 243302400);
        int*            list = (int*)(ws + 243335168);
        int*            pos  = (int*)(ws + 243466240);
        int*            cnt  = (int*)(ws + 243597312);

        conv_bf16<<<(N_SAMP * IN_DIM) / 1024, 256, 0, stream>>>(bb, Abf, N_SAMP * IN_DIM);
        router_kernel<<<N_SAMP / 4, 256, 0, stream>>>(bb, task, temb, rm, gv, gi,
                                                      out + (size_t)N_SAMP * HID);
        compact_kernel<<<NE, 256, 0, stream>>>(gi, list, pos, cnt);

        transpose_conv<<<dim3(IN_DIM / 64, HID / 64), 256, 0, stream>>>(W1, W1Ta, IN_DIM, HID);
        transpose_conv<<<dim3(IN_DIM / 64, HID / 64), 256, 0, stream>>>(
            W1 + (size_t)1 * IN_DIM * HID, W1Tb, IN_DIM, HID);
        // D0: [G1(0)->h0 | G1(1)->h1]
        gemm256_dual_g1g1<<<512, 512, lds_bytes, stream>>>(
            Abf, W1Ta, b1, h0, list, cnt,
            W1Tb, b1 + HID, h1, list + N_SAMP, cnt + 1);

        transpose_conv<<<dim3(HID / 64, HID / 64), 256, 0, stream>>>(W2, W2Ta, HID, HID);
        transpose_conv<<<dim3(IN_DIM / 64, HID / 64), 256, 0, stream>>>(
            W1 + (size_t)2 * IN_DIM * HID, W1Ta, IN_DIM, HID);
        // D1: [G2(0): h0->obf0 | G1(2)->h2]
        gemm256_dual<<<512, 512, lds_bytes, stream>>>(
            h0, W2Ta, b2, obf, cnt,
            Abf, W1Ta, b1 + 2 * HID, h2, list + (size_t)2 * N_SAMP, cnt + 2);

        transpose_conv<<<dim3(HID / 64, HID / 64), 256, 0, stream>>>(
            W2 + (size_t)1 * HID * HID, W2Tb, HID, HID);
        transpose_conv<<<dim3(IN_DIM / 64, HID / 64), 256, 0, stream>>>(
            W1 + (size_t)3 * IN_DIM * HID, W1Tb, IN_DIM, HID);
        // D2: [G2(1): h1->obf1 | G1(3)->h3]
        gemm256_dual<<<512, 512, lds_bytes, stream>>>(
            h1, W2Tb, b2 + HID, obf + (size_t)1 * N_SAMP * HID, cnt + 1,
            Abf, W1Tb, b1 + 3 * HID, h3, list + (size_t)3 * N_SAMP, cnt + 3);

        transpose_conv<<<dim3(HID / 64, HID / 64), 256, 0, stream>>>(
            W2 + (size_t)2 * HID * HID, W2Ta, HID, HID);
        transpose_conv<<<dim3(HID / 64, HID / 64), 256, 0, stream>>>(
            W2 + (size_t)3 * HID * HID, W2Tb, HID, HID);
        // D3: [G2(2): h2->obf2 | G2(3): h3->obf3]
        gemm256_dual_g2g2<<<512, 512, lds_bytes, stream>>>(
            h2, W2Ta, b2 + 2 * HID, obf + (size_t)2 * N_SAMP * HID, cnt + 2,
            h3, W2Tb, b2 + 3 * HID, obf + (size_t)3 * N_SAMP * HID, cnt + 3);

        gs_kernel<<<N_SAMP / 4, 256, 0, stream>>>(obf, gv, gi, pos, out);
    } else {
        // ===== fallback: exact round-9 structure, ~197.5 MB (proven) =====
        unsigned short* obf  = (unsigned short*)(ws + 0);
        unsigned short* Abf  = (unsigned short*)(ws + 134217728);
        unsigned short* hbfA = (unsigned short*)(ws + 150994944);
        unsigned short* W1T  = (unsigned short*)(ws + 184549376);
        unsigned short* W2T  = (unsigned short*)(ws + 188743680);
        float*          gv   = (float*)(ws + 197132288);
        int*            gi   = (int*)(ws + 197165056);
        int*            list = (int*)(ws + 197197824);
        int*            pos  = (int*)(ws + 197328896);
        int*            cnt  = (int*)(ws + 197459968);
        unsigned short* hbfB = obf + (size_t)3 * N_SAMP * HID;
        auto hbf = [&](int e) { return (e & 1) ? hbfA : hbfB; };

        conv_bf16<<<(N_SAMP * IN_DIM) / 1024, 256, 0, stream>>>(bb, Abf, N_SAMP * IN_DIM);
        router_kernel<<<N_SAMP / 4, 256, 0, stream>>>(bb, task, temb, rm, gv, gi,
                                                      out + (size_t)N_SAMP * HID);
        compact_kernel<<<NE, 256, 0, stream>>>(gi, list, pos, cnt);

        transpose_conv<<<dim3(IN_DIM / 64, HID / 64), 256, 0, stream>>>(W1, W1T, IN_DIM, HID);
        gemm256<IN_DIM><<<256, 512, lds_bytes, stream>>>(
            Abf, W1T, b1, hbf(0), HID, list, cnt);

        for (int e = 0; e < 3; ++e) {
            transpose_conv<<<dim3(HID / 64, HID / 64), 256, 0, stream>>>(
                W2 + (size_t)e * HID * HID, W2T, HID, HID);
            transpose_conv<<<dim3(IN_DIM / 64, HID / 64), 256, 0, stream>>>(
                W1 + (size_t)(e + 1) * IN_DIM * HID, W1T, IN_DIM, HID);
            gemm256_dual<<<512, 512, lds_bytes, stream>>>(
                hbf(e), W2T, b2 + (size_t)e * HID, obf + (size_t)e * N_SAMP * HID, cnt + e,
                Abf, W1T, b1 + (size_t)(e + 1) * HID, hbf(e + 1),
                list + (size_t)(e + 1) * N_SAMP, cnt + e + 1);
        }

        transpose_conv<<<dim3(HID / 64, HID / 64), 256, 0, stream>>>(
            W2 + (size_t)3 * HID * HID, W2T, HID, HID);
        gemm256<HID><<<256, 512, lds_bytes, stream>>>(
            hbf(3), W2T, b2 + (size_t)3 * HID, obf + (size_t)3 * N_SAMP * HID, HID,
            nullptr, cnt + 3);

        gs_kernel<<<N_SAMP / 4, 256, 0, stream>>>(obf, gv, gi, pos, out);
    }
}

// Round 11
// 484.835 us; speedup vs baseline: 1.2937x; 1.0267x over previous
//
#include <hip/hip_runtime.h>
#include <hip/hip_bf16.h>
#include <cstdint>

#define N_SAMP 8192
#define IN_DIM 1024
#define HID    2048
#define NE     4

typedef __attribute__((ext_vector_type(8))) __bf16 bf16x8;
typedef __attribute__((ext_vector_type(4))) float  f32x4;

#define MFMA16 __builtin_amdgcn_mfma_f32_16x16x32_bf16

__device__ __forceinline__ unsigned short f2b(float f) {
    unsigned u = __float_as_uint(f);
    u += 0x7fff + ((u >> 16) & 1);          // RNE, finite inputs only
    return (unsigned short)(u >> 16);
}
__device__ __forceinline__ float b2f(unsigned short s) {
    return __uint_as_float(((unsigned)s) << 16);
}

// async global->LDS, 16B per lane; LDS dest is wave-uniform base (+lane*16 by HW)
__device__ __forceinline__ void gll16(const void* g, void* l) {
    __builtin_amdgcn_global_load_lds(
        (const __attribute__((address_space(1))) void*)g,
        (__attribute__((address_space(3))) void*)l,
        16, 0, 0);
}

// LDS byte swizzle for 128B-row tiles: bits 4-6 ^= row bits 0-2 (byte bits 7-9).
// Involution; keeps 16B alignment; conflict-free ds_read_b128 (verified r6: conflicts=0).
__device__ __forceinline__ int swz(int byte) {
    return byte ^ (((byte >> 7) & 7) << 4);
}

// ---------------- f32 -> bf16 elementwise ----------------
__global__ void conv_bf16(const float* __restrict__ s, unsigned short* __restrict__ d, int n) {
    int i = (blockIdx.x * blockDim.x + threadIdx.x) * 4;
    if (i >= n) return;
    float4 v = *(const float4*)&s[i];
    ushort4 o;
    o.x = f2b(v.x); o.y = f2b(v.y); o.z = f2b(v.z); o.w = f2b(v.w);
    *(ushort4*)&d[i] = o;
}

// ---------------- transpose + convert: src [K][M] f32 -> dst [M][K] bf16 ----------------
__global__ void transpose_conv(const float* __restrict__ src, unsigned short* __restrict__ dst,
                               int K, int M) {
    __shared__ float tile[64][65];
    const int k0 = blockIdx.x * 64, m0 = blockIdx.y * 64;
    const int t  = threadIdx.x;
    const int tc = t & 15, tr = t >> 4;
    const float* s = src + (size_t)k0 * M + m0;
    #pragma unroll
    for (int r = tr; r < 64; r += 16) {
        float4 v = *(const float4*)&s[(size_t)r * M + tc * 4];
        tile[r][tc * 4 + 0] = v.x; tile[r][tc * 4 + 1] = v.y;
        tile[r][tc * 4 + 2] = v.z; tile[r][tc * 4 + 3] = v.w;
    }
    __syncthreads();
    unsigned short* d = dst + (size_t)m0 * K + k0;
    #pragma unroll
    for (int r = tr; r < 64; r += 16) {
        ushort4 o;
        o.x = f2b(tile[tc * 4 + 0][r]); o.y = f2b(tile[tc * 4 + 1][r]);
        o.z = f2b(tile[tc * 4 + 2][r]); o.w = f2b(tile[tc * 4 + 3][r]);
        *(ushort4*)&d[(size_t)r * K + tc * 4] = o;
    }
}

// ---------------- router: fp32 logits, softmax, first-max argmax, reg_loss ----------------
__global__ __launch_bounds__(256) void router_kernel(
    const float* __restrict__ bb, const int* __restrict__ task,
    const float* __restrict__ temb, const float* __restrict__ rm,
    float* __restrict__ gval, int* __restrict__ gidx,
    float* __restrict__ regout) {
    const int t = threadIdx.x, wave = t >> 6, lane = t & 63;
    const int n = blockIdx.x * 4 + wave;
    const int tk = task[n];
    float a0 = 0.f, a1 = 0.f, a2 = 0.f, a3 = 0.f;
    for (int i = lane; i < IN_DIM + 100; i += 64) {
        float x = (i < IN_DIM) ? bb[(size_t)n * IN_DIM + i] : temb[tk * 100 + (i - IN_DIM)];
        float4 r = *(const float4*)&rm[i * 4];
        a0 += x * r.x; a1 += x * r.y; a2 += x * r.z; a3 += x * r.w;
    }
    #pragma unroll
    for (int o = 32; o; o >>= 1) {
        a0 += __shfl_xor(a0, o); a1 += __shfl_xor(a1, o);
        a2 += __shfl_xor(a2, o); a3 += __shfl_xor(a3, o);
    }
    if (lane == 0) {
        float l[4] = {a0, a1, a2, a3};
        float mx = fmaxf(fmaxf(l[0], l[1]), fmaxf(l[2], l[3]));
        float ex[4], s = 0.f;
        #pragma unroll
        for (int j = 0; j < 4; j++) { ex[j] = expf(l[j] - mx); s += ex[j]; }
        int bi = 0; float bw = ex[0];
        #pragma unroll
        for (int j = 1; j < 4; j++) if (ex[j] > bw) { bw = ex[j]; bi = j; }
        float g = bw / s;
        gval[n] = g;
        gidx[n] = bi;
        regout[n] = -0.0025f * (logf(g + 1e-6f) + 3.0f * logf(1e-6f));
    }
}

// ---------------- per-expert compaction: list_e = {n : idx[n] >= e}; pad to mult 256 --------
__global__ void compact_kernel(const int* __restrict__ gidx, int* __restrict__ list,
                               int* __restrict__ pos, int* __restrict__ cnt) {
    const int e = blockIdx.x;
    const int t = threadIdx.x, lane = t & 63, wave = t >> 6;
    __shared__ int wbase[4];
    __shared__ int running;
    if (t == 0) running = 0;
    __syncthreads();
    int* le = list + (size_t)e * N_SAMP;
    int* pe = pos + (size_t)e * N_SAMP;
    for (int base = 0; base < N_SAMP; base += 256) {
        const int n = base + t;
        const bool f = gidx[n] >= e;
        unsigned long long m = __ballot(f);
        int rank = __popcll(m & ((1ULL << lane) - 1ULL));
        if (lane == 0) wbase[wave] = __popcll(m);
        __syncthreads();
        int wb = 0;
        #pragma unroll
        for (int w = 0; w < 4; w++) if (w < wave) wb += wbase[w];
        int tot = wbase[0] + wbase[1] + wbase[2] + wbase[3];
        int o = running + wb + rank;
        if (f) { le[o] = n; pe[n] = o; }
        __syncthreads();
        if (t == 0) running += tot;
        __syncthreads();
    }
    const int c = running;
    if (t == 0) cnt[e] = c;
    const int padded = (c + 255) & ~255;
    for (int i = c + t; i < padded && i < N_SAMP; i += 256) le[i] = 0;
}

// ================= 256x256 8-phase bf16 MFMA GEMM core (KT = compile-time K) =================
template<int KT>
__device__ __forceinline__ void gemm_core(
    const unsigned short* __restrict__ A, const unsigned short* __restrict__ BT,
    const float* __restrict__ bias, unsigned short* __restrict__ C,
    int M, const int* __restrict__ rowlist, const int* __restrict__ cntp,
    int bid, char* lds_) {
    constexpr int nt = KT / 64;
    const int cnt = *cntp;
    const int mb = bid & 7, nb = bid >> 3;
    const int n0 = nb * 256;
    if (n0 >= cnt) return;
    const int m0 = mb * 256;
    const int t = threadIdx.x;
    const int w = t >> 6, lane = t & 63;
    const int wm = w >> 2, wn = w & 3;          // wave -> (sample-half, m-quarter)
    const int lrow = lane & 15, kg = lane >> 4;

    int rr[2], cb[2];
    #pragma unroll
    for (int q = 0; q < 2; q++) {
        int Ps = swz((t + q * 512) * 16);
        rr[q] = Ps >> 7;
        cb[q] = Ps & 127;
    }
    const char* aS[2][2];
    const char* bS[2][2];
    #pragma unroll
    for (int h = 0; h < 2; h++)
        #pragma unroll
        for (int q = 0; q < 2; q++) {
            int r = n0 + h * 128 + rr[q];
            int ga = rowlist ? rowlist[r] : r;
            aS[h][q] = (const char*)A + (size_t)ga * (KT * 2) + cb[q];
            bS[h][q] = (const char*)BT + (size_t)(m0 + h * 128 + rr[q]) * (KT * 2) + cb[q];
        }

    auto stageA = [&](int buf, int h, int kt) {
        gll16(aS[h][0] + kt * 128, lds_ + buf * 65536 + h * 16384 + w * 1024);
        gll16(aS[h][1] + kt * 128, lds_ + buf * 65536 + h * 16384 + 8192 + w * 1024);
    };
    auto stageB = [&](int buf, int h, int kt) {
        gll16(bS[h][0] + kt * 128, lds_ + buf * 65536 + 32768 + h * 16384 + w * 1024);
        gll16(bS[h][1] + kt * 128, lds_ + buf * 65536 + 32768 + h * 16384 + 8192 + w * 1024);
    };

    const int mask = (lrow & 7) << 4;
    const int c0 = (kg * 16) ^ mask;
    const int c1 = (kg * 16 + 64) ^ mask;
    const char* const pA[2] = { lds_ + wm * 16384 + lrow * 128 + c0,
                                lds_ + wm * 16384 + lrow * 128 + c1 };
    const int browB = (wn & 1) * 64 + lrow;
    const char* const pB[2] = { lds_ + 32768 + (wn >> 1) * 16384 + browB * 128 + c0,
                                lds_ + 32768 + (wn >> 1) * 16384 + browB * 128 + c1 };
    auto ldA = [&](int buf, int i, int kk) -> bf16x8 {
        return *(const bf16x8*)(pA[kk] + buf * 65536 + i * 2048);
    };
    auto ldB = [&](int buf, int j, int kk) -> bf16x8 {
        return *(const bf16x8*)(pB[kk] + buf * 65536 + j * 2048);
    };

    f32x4 acc[8][4];
    #pragma unroll
    for (int i = 0; i < 8; i++)
        #pragma unroll
        for (int j = 0; j < 4; j++) acc[i][j] = (f32x4){0.f, 0.f, 0.f, 0.f};

    stageA(0, 0, 0); stageA(0, 1, 0); stageB(0, 0, 0); stageB(0, 1, 0);
    stageA(1, 0, 1); stageA(1, 1, 1); stageB(1, 0, 1);
    asm volatile("s_waitcnt vmcnt(6)" ::: "memory");
    __builtin_amdgcn_s_barrier();

    bf16x8 af[4][2], bfr[4][2];
    auto tile = [&](int kt, int buf) {
        // ---- phase 0: i0-3 x j0-1 (12 ds_reads); stage B1(t+1) -> buf^1
        #pragma unroll
        for (int i = 0; i < 4; i++) { af[i][0] = ldA(buf, i, 0); af[i][1] = ldA(buf, i, 1); }
        #pragma unroll
        for (int j = 0; j < 2; j++) { bfr[j][0] = ldB(buf, j, 0); bfr[j][1] = ldB(buf, j, 1); }
        if (kt + 1 < nt) stageB(buf ^ 1, 1, kt + 1);
        __builtin_amdgcn_s_barrier();
        __builtin_amdgcn_s_setprio(1);
        #pragma unroll
        for (int i = 0; i < 4; i++)
            #pragma unroll
            for (int j = 0; j < 2; j++) {
                acc[i][j] = MFMA16(af[i][0], bfr[j][0], acc[i][j], 0, 0, 0);
                acc[i][j] = MFMA16(af[i][1], bfr[j][1], acc[i][j], 0, 0, 0);
            }
        __builtin_amdgcn_s_setprio(0);
        __builtin_amdgcn_s_barrier();
        // ---- phase 1: i0-3 x j2-3 (4 ds_reads)
        #pragma unroll
        for (int j = 2; j < 4; j++) { bfr[j][0] = ldB(buf, j, 0); bfr[j][1] = ldB(buf, j, 1); }
        __builtin_amdgcn_s_barrier();
        __builtin_amdgcn_s_setprio(1);
        #pragma unroll
        for (int i = 0; i < 4; i++)
            #pragma unroll
            for (int j = 0; j < 2; j++) {
                acc[i][2 + j] = MFMA16(af[i][0], bfr[2 + j][0], acc[i][2 + j], 0, 0, 0);
                acc[i][2 + j] = MFMA16(af[i][1], bfr[2 + j][1], acc[i][2 + j], 0, 0, 0);
            }
        __builtin_amdgcn_s_setprio(0);
        __builtin_amdgcn_s_barrier();
        // ---- phase 2: i4-7 x j0-1 (8 ds_reads, af reused); stage B0(t+2) -> buf
        #pragma unroll
        for (int i = 0; i < 4; i++) { af[i][0] = ldA(buf, 4 + i, 0); af[i][1] = ldA(buf, 4 + i, 1); }
        if (kt + 2 < nt) stageB(buf, 0, kt + 2);
        __builtin_amdgcn_s_barrier();
        __builtin_amdgcn_s_setprio(1);
        #pragma unroll
        for (int i = 0; i < 4; i++)
            #pragma unroll
            for (int j = 0; j < 2; j++) {
                acc[4 + i][j] = MFMA16(af[i][0], bfr[j][0], acc[4 + i][j], 0, 0, 0);
                acc[4 + i][j] = MFMA16(af[i][1], bfr[j][1], acc[4 + i][j], 0, 0, 0);
            }
        __builtin_amdgcn_s_setprio(0);
        __builtin_amdgcn_s_barrier();
        // ---- phase 3: i4-7 x j2-3 (0 ds_reads); stage A0,A1(t+2) -> buf
        if (kt + 2 < nt) { stageA(buf, 0, kt + 2); stageA(buf, 1, kt + 2); }
        __builtin_amdgcn_s_barrier();
        __builtin_amdgcn_s_setprio(1);
        #pragma unroll
        for (int i = 0; i < 4; i++)
            #pragma unroll
            for (int j = 0; j < 2; j++) {
                acc[4 + i][2 + j] = MFMA16(af[i][0], bfr[2 + j][0], acc[4 + i][2 + j], 0, 0, 0);
                acc[4 + i][2 + j] = MFMA16(af[i][1], bfr[2 + j][1], acc[4 + i][2 + j], 0, 0, 0);
            }
        __builtin_amdgcn_s_setprio(0);
        if (kt < nt - 2) asm volatile("s_waitcnt vmcnt(6)" ::: "memory");
        else             asm volatile("s_waitcnt vmcnt(0)" ::: "memory");
        __builtin_amdgcn_s_barrier();
    };
    for (int kt = 0; kt < nt; kt += 2) { tile(kt, 0); tile(kt + 1, 1); }

    // epilogue: C/D layout col=lane&15, row=(lane>>4)*4+q  (m89-verified)
    float bv[4];
    #pragma unroll
    for (int j = 0; j < 4; j++)
        bv[j] = bias[m0 + wn * 64 + j * 16 + lrow];
    #pragma unroll
    for (int i = 0; i < 8; i++) {
        const int srow0 = n0 + wm * 128 + i * 16 + kg * 4;
        #pragma unroll
        for (int j = 0; j < 4; j++) {
            const int col = m0 + wn * 64 + j * 16 + lrow;
            #pragma unroll
            for (int q = 0; q < 4; q++) {
                if (srow0 + q < cnt) {
                    float x = acc[i][j][q] + bv[j];
                    C[(size_t)(srow0 + q) * M + col] = f2b(fmaxf(x, 0.f));
                }
            }
        }
    }
}

template<int KT>
__global__ __launch_bounds__(512, 2) void gemm256(
    const unsigned short* __restrict__ A, const unsigned short* __restrict__ BT,
    const float* __restrict__ bias, unsigned short* __restrict__ C,
    int M, const int* __restrict__ rowlist, const int* __restrict__ cntp) {
    extern __shared__ char lds_[];
    gemm_core<KT>(A, BT, bias, C, M, rowlist, cntp, blockIdx.x, lds_);
}

// packed: bids [0,256) = G2 (K=HID);  bids [256,512) = G1 (K=IN_DIM)
__global__ __launch_bounds__(512, 2) void gemm256_dual(
    const unsigned short* __restrict__ A2, const unsigned short* __restrict__ BT2,
    const float* __restrict__ bias2, unsigned short* __restrict__ C2,
    const int* __restrict__ cnt2,
    const unsigned short* __restrict__ A1, const unsigned short* __restrict__ BT1,
    const float* __restrict__ bias1, unsigned short* __restrict__ C1,
    const int* __restrict__ rowlist1, const int* __restrict__ cnt1) {
    extern __shared__ char lds_[];
    const int bid = blockIdx.x;
    if (bid < 256) {
        gemm_core<HID>(A2, BT2, bias2, C2, HID, nullptr, cnt2, bid, lds_);
    } else {
        gemm_core<IN_DIM>(A1, BT1, bias1, C1, HID, rowlist1, cnt1, bid - 256, lds_);
    }
}

// packed: two G1 jobs (both K=IN_DIM, shared A)
__global__ __launch_bounds__(512, 2) void gemm256_dual_g1g1(
    const unsigned short* __restrict__ A,
    const unsigned short* __restrict__ BTa, const float* __restrict__ biasa,
    unsigned short* __restrict__ Ca, const int* __restrict__ rla, const int* __restrict__ cnta,
    const unsigned short* __restrict__ BTb, const float* __restrict__ biasb,
    unsigned short* __restrict__ Cb, const int* __restrict__ rlb, const int* __restrict__ cntb) {
    extern __shared__ char lds_[];
    const int bid = blockIdx.x;
    if (bid < 256) {
        gemm_core<IN_DIM>(A, BTa, biasa, Ca, HID, rla, cnta, bid, lds_);
    } else {
        gemm_core<IN_DIM>(A, BTb, biasb, Cb, HID, rlb, cntb, bid - 256, lds_);
    }
}

// packed: two G2 jobs (both K=HID)
__global__ __launch_bounds__(512, 2) void gemm256_dual_g2g2(
    const unsigned short* __restrict__ Aa, const unsigned short* __restrict__ BTa,
    const float* __restrict__ biasa, unsigned short* __restrict__ Ca, const int* __restrict__ cnta,
    const unsigned short* __restrict__ Ab, const unsigned short* __restrict__ BTb,
    const float* __restrict__ biasb, unsigned short* __restrict__ Cb, const int* __restrict__ cntb) {
    extern __shared__ char lds_[];
    const int bid = blockIdx.x;
    if (bid < 256) {
        gemm_core<HID>(Aa, BTa, biasa, Ca, HID, nullptr, cnta, bid, lds_);
    } else {
        gemm_core<HID>(Ab, BTb, biasb, Cb, HID, nullptr, cntb, bid - 256, lds_);
    }
}

// ---------------- Gram-Schmidt + gather: one wave per sample (compact obf via pos) ------------
// __launch_bounds__(256,1): without it hipcc compiles for 1024-thread blocks and caps
// VGPRs at 64 -> the 128-float basis state spills to scratch (r10: 140us, WRITE 93.7MB).
__global__ __launch_bounds__(256, 1) void gs_kernel(
    const unsigned short* __restrict__ eo, const float* __restrict__ gval,
    const int* __restrict__ gidx, const int* __restrict__ pos,
    float* __restrict__ dout) {
    const int t = threadIdx.x, wave = t >> 6, lane = t & 63;
    const int n = blockIdx.x * 4 + wave;
    const int idx = gidx[n];
    const float g = gval[n];

    float v[32], b0[32], b1[32], b2[32];

    auto loadv = [&](float* dst, int e) {
        const size_t row = pos[(size_t)e * N_SAMP + n];
        const unsigned short* p = eo + ((size_t)e * N_SAMP + row) * HID + lane * 8;
        #pragma unroll
        for (int c = 0; c < 4; c++) {
            uint4 u = *(const uint4*)(p + c * 512);
            const unsigned short* us = (const unsigned short*)&u;
            #pragma unroll
            for (int j = 0; j < 8; j++) dst[c * 8 + j] = b2f(us[j]);
        }
    };
    auto wdot = [&](const float* x, const float* y) -> float {
        float s = 0.f;
        #pragma unroll
        for (int k = 0; k < 32; k++) s += x[k] * y[k];
        #pragma unroll
        for (int o = 32; o; o >>= 1) s += __shfl_xor(s, o);
        return s;
    };
    auto storev = [&](const float* b) {
        float* o = dout + (size_t)n * HID + lane * 8;
        #pragma unroll
        for (int c = 0; c < 4; c++) {
            float4 x0, x1;
            x0.x = g * b[c * 8 + 0]; x0.y = g * b[c * 8 + 1];
            x0.z = g * b[c * 8 + 2]; x0.w = g * b[c * 8 + 3];
            x1.x = g * b[c * 8 + 4]; x1.y = g * b[c * 8 + 5];
            x1.z = g * b[c * 8 + 6]; x1.w = g * b[c * 8 + 7];
            *(float4*)(o + c * 512) = x0;
            *(float4*)(o + c * 512 + 4) = x1;
        }
    };

    loadv(v, 0);
    float inv = 1.f / sqrtf(wdot(v, v));
    #pragma unroll
    for (int k = 0; k < 32; k++) b0[k] = v[k] * inv;
    if (idx == 0) { storev(b0); return; }
    loadv(v, 1);
    {
        float cc0 = wdot(v, b0);
        #pragma unroll
        for (int k = 0; k < 32; k++) v[k] -= cc0 * b0[k];
        inv = 1.f / sqrtf(wdot(v, v));
        #pragma unroll
        for (int k = 0; k < 32; k++) b1[k] = v[k] * inv;
    }
    if (idx == 1) { storev(b1); return; }
    loadv(v, 2);
    {
        float cc0 = wdot(v, b0);
        float cc1 = wdot(v, b1);
        #pragma unroll
        for (int k = 0; k < 32; k++) v[k] -= cc0 * b0[k] + cc1 * b1[k];
        inv = 1.f / sqrtf(wdot(v, v));
        #pragma unroll
        for (int k = 0; k < 32; k++) b2[k] = v[k] * inv;
    }
    if (idx == 2) { storev(b2); return; }
    loadv(v, 3);
    {
        float cc0 = wdot(v, b0);
        float cc1 = wdot(v, b1);
        float cc2 = wdot(v, b2);
        #pragma unroll
        for (int k = 0; k < 32; k++) v[k] -= cc0 * b0[k] + cc1 * b1[k] + cc2 * b2[k];
        inv = 1.f / sqrtf(wdot(v, v));
        #pragma unroll
        for (int k = 0; k < 32; k++) v[k] *= inv;
    }
    storev(v);
}

extern "C" void kernel_launch(void* const* d_in, const int* in_sizes, int n_in,
                              void* d_out, int out_size, void* d_ws, size_t ws_size,
                              hipStream_t stream) {
    const float* bb   = (const float*)d_in[0];
    const int*   task = (const int*)d_in[1];
    const float* temb = (const float*)d_in[2];
    const float* rm   = (const float*)d_in[3];
    const float* W1   = (const float*)d_in[4];
    const float* b1   = (const float*)d_in[5];
    const float* W2   = (const float*)d_in[6];
    const float* b2   = (const float*)d_in[7];
    float* out = (float*)d_out;
    char* ws = (char*)d_ws;

    const size_t lds_bytes = 131072;
    const size_t PLAN_A_NEED = 243597376;

    if (ws_size >= PLAN_A_NEED) {
        // ===== Plan A: fully packed GEMM schedule, ~243.6 MB =====
        // D0:[G1(0)|G1(1)]  D1:[G2(0)|G1(2)]  D2:[G2(1)|G1(3)]  D3:[G2(2)|G2(3)]
        unsigned short* obf  = (unsigned short*)(ws + 0);           // 128 MB [E][N][HID]
        unsigned short* h0   = (unsigned short*)(ws + 33554432);    // = obf[1] slot
        unsigned short* h1   = (unsigned short*)(ws + 67108864);    // = obf[2] slot
        unsigned short* Abf  = (unsigned short*)(ws + 134217728);   // 16 MB
        unsigned short* h2   = (unsigned short*)(ws + 150994944);   // 32 MB
        unsigned short* h3   = (unsigned short*)(ws + 184549376);   // 32 MB
        unsigned short* W1Ta = (unsigned short*)(ws + 218103808);   // 4 MB
        unsigned short* W1Tb = (unsigned short*)(ws + 222298112);   // 4 MB
        unsigned short* W2Ta = (unsigned short*)(ws + 226492416);   // 8 MB
        unsigned short* W2Tb = (unsigned short*)(ws + 234881024);   // 8 MB
        float*          gv   = (float*)(ws + 243269632);
        int*            gi   = (int*)(ws + 243302400);
        int*            list = (int*)(ws + 243335168);
        int*            pos  = (int*)(ws + 243466240);
        int*            cnt  = (int*)(ws + 243597312);

        conv_bf16<<<(N_SAMP * IN_DIM) / 1024, 256, 0, stream>>>(bb, Abf, N_SAMP * IN_DIM);
        router_kernel<<<N_SAMP / 4, 256, 0, stream>>>(bb, task, temb, rm, gv, gi,
                                                      out + (size_t)N_SAMP * HID);
        compact_kernel<<<NE, 256, 0, stream>>>(gi, list, pos, cnt);

        transpose_conv<<<dim3(IN_DIM / 64, HID / 64), 256, 0, stream>>>(W1, W1Ta, IN_DIM, HID);
        transpose_conv<<<dim3(IN_DIM / 64, HID / 64), 256, 0, stream>>>(
            W1 + (size_t)1 * IN_DIM * HID, W1Tb, IN_DIM, HID);
        // D0: [G1(0)->h0 | G1(1)->h1]
        gemm256_dual_g1g1<<<512, 512, lds_bytes, stream>>>(
            Abf, W1Ta, b1, h0, list, cnt,
            W1Tb, b1 + HID, h1, list + N_SAMP, cnt + 1);

        transpose_conv<<<dim3(HID / 64, HID / 64), 256, 0, stream>>>(W2, W2Ta, HID, HID);
        transpose_conv<<<dim3(IN_DIM / 64, HID / 64), 256, 0, stream>>>(
            W1 + (size_t)2 * IN_DIM * HID, W1Ta, IN_DIM, HID);
        // D1: [G2(0): h0->obf0 | G1(2)->h2]
        gemm256_dual<<<512, 512, lds_bytes, stream>>>(
            h0, W2Ta, b2, obf, cnt,
            Abf, W1Ta, b1 + 2 * HID, h2, list + (size_t)2 * N_SAMP, cnt + 2);

        transpose_conv<<<dim3(HID / 64, HID / 64), 256, 0, stream>>>(
            W2 + (size_t)1 * HID * HID, W2Tb, HID, HID);
        transpose_conv<<<dim3(IN_DIM / 64, HID / 64), 256, 0, stream>>>(
            W1 + (size_t)3 * IN_DIM * HID, W1Tb, IN_DIM, HID);
        // D2: [G2(1): h1->obf1 | G1(3)->h3]
        gemm256_dual<<<512, 512, lds_bytes, stream>>>(
            h1, W2Tb, b2 + HID, obf + (size_t)1 * N_SAMP * HID, cnt + 1,
            Abf, W1Tb, b1 + 3 * HID, h3, list + (size_t)3 * N_SAMP, cnt + 3);

        transpose_conv<<<dim3(HID / 64, HID / 64), 256, 0, stream>>>(
            W2 + (size_t)2 * HID * HID, W2Ta, HID, HID);
        transpose_conv<<<dim3(HID / 64, HID / 64), 256, 0, stream>>>(
            W2 + (size_t)3 * HID * HID, W2Tb, HID, HID);
        // D3: [G2(2): h2->obf2 | G2(3): h3->obf3]
        gemm256_dual_g2g2<<<512, 512, lds_bytes, stream>>>(
            h2, W2Ta, b2 + 2 * HID, obf + (size_t)2 * N_SAMP * HID, cnt + 2,
            h3, W2Tb, b2 + 3 * HID, obf + (size_t)3 * N_SAMP * HID, cnt + 3);

        gs_kernel<<<N_SAMP / 4, 256, 0, stream>>>(obf, gv, gi, pos, out);
    } else {
        // ===== fallback: round-9 structure, ~197.5 MB (proven) =====
        unsigned short* obf  = (unsigned short*)(ws + 0);
        unsigned short* Abf  = (unsigned short*)(ws + 134217728);
        unsigned short* hbfA = (unsigned short*)(ws + 150994944);
        unsigned short* W1T  = (unsigned short*)(ws + 184549376);
        unsigned short* W2T  = (unsigned short*)(ws + 188743680);
        float*          gv   = (float*)(ws + 197132288);
        int*            gi   = (int*)(ws + 197165056);
        int*            list = (int*)(ws + 197197824);
        int*            pos  = (int*)(ws + 197328896);
        int*            cnt  = (int*)(ws + 197459968);
        unsigned short* hbfB = obf + (size_t)3 * N_SAMP * HID;
        auto hbf = [&](int e) { return (e & 1) ? hbfA : hbfB; };

        conv_bf16<<<(N_SAMP * IN_DIM) / 1024, 256, 0, stream>>>(bb, Abf, N_SAMP * IN_DIM);
        router_kernel<<<N_SAMP / 4, 256, 0, stream>>>(bb, task, temb, rm, gv, gi,
                                                      out + (size_t)N_SAMP * HID);
        compact_kernel<<<NE, 256, 0, stream>>>(gi, list, pos, cnt);

        transpose_conv<<<dim3(IN_DIM / 64, HID / 64), 256, 0, stream>>>(W1, W1T, IN_DIM, HID);
        gemm256<IN_DIM><<<256, 512, lds_bytes, stream>>>(
            Abf, W1T, b1, hbf(0), HID, list, cnt);

        for (int e = 0; e < 3; ++e) {
            transpose_conv<<<dim3(HID / 64, HID / 64), 256, 0, stream>>>(
                W2 + (size_t)e * HID * HID, W2T, HID, HID);
            transpose_conv<<<dim3(IN_DIM / 64, HID / 64), 256, 0, stream>>>(
                W1 + (size_t)(e + 1) * IN_DIM * HID, W1T, IN_DIM, HID);
            gemm256_dual<<<512, 512, lds_bytes, stream>>>(
                hbf(e), W2T, b2 + (size_t)e * HID, obf + (size_t)e * N_SAMP * HID, cnt + e,
                Abf, W1T, b1 + (size_t)(e + 1) * HID, hbf(e + 1),
                list + (size_t)(e + 1) * N_SAMP, cnt + e + 1);
        }

        transpose_conv<<<dim3(HID / 64, HID / 64), 256, 0, stream>>>(
            W2 + (size_t)3 * HID * HID, W2T, HID, HID);
        gemm256<HID><<<256, 512, lds_bytes, stream>>>(
            hbf(3), W2T, b2 + (size_t)3 * HID, obf + (size_t)3 * N_SAMP * HID, HID,
            nullptr, cnt + 3);

        gs_kernel<<<N_SAMP / 4, 256, 0, stream>>>(obf, gv, gi, pos, out);
    }
}

// Round 12
// 471.613 us; speedup vs baseline: 1.3299x; 1.0280x over previous
//
#include <hip/hip_runtime.h>
#include <hip/hip_bf16.h>
#include <cstdint>

#define N_SAMP 8192
#define IN_DIM 1024
#define HID    2048
#define NE     4

typedef __attribute__((ext_vector_type(8))) __bf16 bf16x8;
typedef __attribute__((ext_vector_type(4))) float  f32x4;

#define MFMA16 __builtin_amdgcn_mfma_f32_16x16x32_bf16

__device__ __forceinline__ unsigned short f2b(float f) {
    unsigned u = __float_as_uint(f);
    u += 0x7fff + ((u >> 16) & 1);          // RNE, finite inputs only
    return (unsigned short)(u >> 16);
}
__device__ __forceinline__ float b2f(unsigned short s) {
    return __uint_as_float(((unsigned)s) << 16);
}

// async global->LDS, 16B per lane; LDS dest is wave-uniform base (+lane*16 by HW)
__device__ __forceinline__ void gll16(const void* g, void* l) {
    __builtin_amdgcn_global_load_lds(
        (const __attribute__((address_space(1))) void*)g,
        (__attribute__((address_space(3))) void*)l,
        16, 0, 0);
}

// LDS byte swizzle for 128B-row tiles: bits 4-6 ^= row bits 0-2 (byte bits 7-9).
// Involution; keeps 16B alignment; conflict-free ds_read_b128 (verified r6: conflicts=0).
__device__ __forceinline__ int swz(int byte) {
    return byte ^ (((byte >> 7) & 7) << 4);
}

// ---------------- f32 -> bf16 elementwise ----------------
__global__ void conv_bf16(const float* __restrict__ s, unsigned short* __restrict__ d, int n) {
    int i = (blockIdx.x * blockDim.x + threadIdx.x) * 4;
    if (i >= n) return;
    float4 v = *(const float4*)&s[i];
    ushort4 o;
    o.x = f2b(v.x); o.y = f2b(v.y); o.z = f2b(v.z); o.w = f2b(v.w);
    *(ushort4*)&d[i] = o;
}

// -------- transpose + convert: src [e][K][M] f32 -> dst [e][M][K] bf16 (z-batched) --------
__global__ void transpose_conv(const float* __restrict__ src, unsigned short* __restrict__ dst,
                               int K, int M, size_t srcStride, size_t dstStride) {
    __shared__ float tile[64][65];
    const int e  = blockIdx.z;
    const int k0 = blockIdx.x * 64, m0 = blockIdx.y * 64;
    const int t  = threadIdx.x;
    const int tc = t & 15, tr = t >> 4;
    const float* s = src + (size_t)e * srcStride + (size_t)k0 * M + m0;
    #pragma unroll
    for (int r = tr; r < 64; r += 16) {
        float4 v = *(const float4*)&s[(size_t)r * M + tc * 4];
        tile[r][tc * 4 + 0] = v.x; tile[r][tc * 4 + 1] = v.y;
        tile[r][tc * 4 + 2] = v.z; tile[r][tc * 4 + 3] = v.w;
    }
    __syncthreads();
    unsigned short* d = dst + (size_t)e * dstStride + (size_t)m0 * K + k0;
    #pragma unroll
    for (int r = tr; r < 64; r += 16) {
        ushort4 o;
        o.x = f2b(tile[tc * 4 + 0][r]); o.y = f2b(tile[tc * 4 + 1][r]);
        o.z = f2b(tile[tc * 4 + 2][r]); o.w = f2b(tile[tc * 4 + 3][r]);
        *(ushort4*)&d[(size_t)r * K + tc * 4] = o;
    }
}

// ---------------- router: fp32 logits, softmax, first-max argmax, reg_loss ----------------
__global__ __launch_bounds__(256) void router_kernel(
    const float* __restrict__ bb, const int* __restrict__ task,
    const float* __restrict__ temb, const float* __restrict__ rm,
    float* __restrict__ gval, int* __restrict__ gidx,
    float* __restrict__ regout) {
    const int t = threadIdx.x, wave = t >> 6, lane = t & 63;
    const int n = blockIdx.x * 4 + wave;
    const int tk = task[n];
    float a0 = 0.f, a1 = 0.f, a2 = 0.f, a3 = 0.f;
    for (int i = lane; i < IN_DIM + 100; i += 64) {
        float x = (i < IN_DIM) ? bb[(size_t)n * IN_DIM + i] : temb[tk * 100 + (i - IN_DIM)];
        float4 r = *(const float4*)&rm[i * 4];
        a0 += x * r.x; a1 += x * r.y; a2 += x * r.z; a3 += x * r.w;
    }
    #pragma unroll
    for (int o = 32; o; o >>= 1) {
        a0 += __shfl_xor(a0, o); a1 += __shfl_xor(a1, o);
        a2 += __shfl_xor(a2, o); a3 += __shfl_xor(a3, o);
    }
    if (lane == 0) {
        float l[4] = {a0, a1, a2, a3};
        float mx = fmaxf(fmaxf(l[0], l[1]), fmaxf(l[2], l[3]));
        float ex[4], s = 0.f;
        #pragma unroll
        for (int j = 0; j < 4; j++) { ex[j] = expf(l[j] - mx); s += ex[j]; }
        int bi = 0; float bw = ex[0];
        #pragma unroll
        for (int j = 1; j < 4; j++) if (ex[j] > bw) { bw = ex[j]; bi = j; }
        float g = bw / s;
        gval[n] = g;
        gidx[n] = bi;
        regout[n] = -0.0025f * (logf(g + 1e-6f) + 3.0f * logf(1e-6f));
    }
}

// ---------------- per-expert compaction: list_e = {n : idx[n] >= e}; pad to mult 256 --------
__global__ void compact_kernel(const int* __restrict__ gidx, int* __restrict__ list,
                               int* __restrict__ pos, int* __restrict__ cnt) {
    const int e = blockIdx.x;
    const int t = threadIdx.x, lane = t & 63, wave = t >> 6;
    __shared__ int wbase[4];
    __shared__ int running;
    if (t == 0) running = 0;
    __syncthreads();
    int* le = list + (size_t)e * N_SAMP;
    int* pe = pos + (size_t)e * N_SAMP;
    for (int base = 0; base < N_SAMP; base += 256) {
        const int n = base + t;
        const bool f = gidx[n] >= e;
        unsigned long long m = __ballot(f);
        int rank = __popcll(m & ((1ULL << lane) - 1ULL));
        if (lane == 0) wbase[wave] = __popcll(m);
        __syncthreads();
        int wb = 0;
        #pragma unroll
        for (int w = 0; w < 4; w++) if (w < wave) wb += wbase[w];
        int tot = wbase[0] + wbase[1] + wbase[2] + wbase[3];
        int o = running + wb + rank;
        if (f) { le[o] = n; pe[n] = o; }
        __syncthreads();
        if (t == 0) running += tot;
        __syncthreads();
    }
    const int c = running;
    if (t == 0) cnt[e] = c;
    const int padded = (c + 255) & ~255;
    for (int i = c + t; i < padded && i < N_SAMP; i += 256) le[i] = 0;
}

// ================= 256x256 8-phase bf16 MFMA GEMM core (KT = compile-time K) =================
template<int KT>
__device__ __forceinline__ void gemm_core(
    const unsigned short* __restrict__ A, const unsigned short* __restrict__ BT,
    const float* __restrict__ bias, unsigned short* __restrict__ C,
    int M, const int* __restrict__ rowlist, const int* __restrict__ cntp,
    int bid, char* lds_) {
    constexpr int nt = KT / 64;
    const int cnt = *cntp;
    const int mb = bid & 7, nb = bid >> 3;
    const int n0 = nb * 256;
    if (n0 >= cnt) return;
    const int m0 = mb * 256;
    const int t = threadIdx.x;
    const int w = t >> 6, lane = t & 63;
    const int wm = w >> 2, wn = w & 3;          // wave -> (sample-half, m-quarter)
    const int lrow = lane & 15, kg = lane >> 4;

    int rr[2], cb[2];
    #pragma unroll
    for (int q = 0; q < 2; q++) {
        int Ps = swz((t + q * 512) * 16);
        rr[q] = Ps >> 7;
        cb[q] = Ps & 127;
    }
    const char* aS[2][2];
    const char* bS[2][2];
    #pragma unroll
    for (int h = 0; h < 2; h++)
        #pragma unroll
        for (int q = 0; q < 2; q++) {
            int r = n0 + h * 128 + rr[q];
            int ga = rowlist ? rowlist[r] : r;
            aS[h][q] = (const char*)A + (size_t)ga * (KT * 2) + cb[q];
            bS[h][q] = (const char*)BT + (size_t)(m0 + h * 128 + rr[q]) * (KT * 2) + cb[q];
        }

    auto stageA = [&](int buf, int h, int kt) {
        gll16(aS[h][0] + kt * 128, lds_ + buf * 65536 + h * 16384 + w * 1024);
        gll16(aS[h][1] + kt * 128, lds_ + buf * 65536 + h * 16384 + 8192 + w * 1024);
    };
    auto stageB = [&](int buf, int h, int kt) {
        gll16(bS[h][0] + kt * 128, lds_ + buf * 65536 + 32768 + h * 16384 + w * 1024);
        gll16(bS[h][1] + kt * 128, lds_ + buf * 65536 + 32768 + h * 16384 + 8192 + w * 1024);
    };

    const int mask = (lrow & 7) << 4;
    const int c0 = (kg * 16) ^ mask;
    const int c1 = (kg * 16 + 64) ^ mask;
    const char* const pA[2] = { lds_ + wm * 16384 + lrow * 128 + c0,
                                lds_ + wm * 16384 + lrow * 128 + c1 };
    const int browB = (wn & 1) * 64 + lrow;
    const char* const pB[2] = { lds_ + 32768 + (wn >> 1) * 16384 + browB * 128 + c0,
                                lds_ + 32768 + (wn >> 1) * 16384 + browB * 128 + c1 };
    auto ldA = [&](int buf, int i, int kk) -> bf16x8 {
        return *(const bf16x8*)(pA[kk] + buf * 65536 + i * 2048);
    };
    auto ldB = [&](int buf, int j, int kk) -> bf16x8 {
        return *(const bf16x8*)(pB[kk] + buf * 65536 + j * 2048);
    };

    f32x4 acc[8][4];
    #pragma unroll
    for (int i = 0; i < 8; i++)
        #pragma unroll
        for (int j = 0; j < 4; j++) acc[i][j] = (f32x4){0.f, 0.f, 0.f, 0.f};

    stageA(0, 0, 0); stageA(0, 1, 0); stageB(0, 0, 0); stageB(0, 1, 0);
    stageA(1, 0, 1); stageA(1, 1, 1); stageB(1, 0, 1);
    asm volatile("s_waitcnt vmcnt(6)" ::: "memory");
    __builtin_amdgcn_s_barrier();

    bf16x8 af[4][2], bfr[4][2];
    auto tile = [&](int kt, int buf) {
        // ---- phase 0: i0-3 x j0-1 (12 ds_reads); stage B1(t+1) -> buf^1
        #pragma unroll
        for (int i = 0; i < 4; i++) { af[i][0] = ldA(buf, i, 0); af[i][1] = ldA(buf, i, 1); }
        #pragma unroll
        for (int j = 0; j < 2; j++) { bfr[j][0] = ldB(buf, j, 0); bfr[j][1] = ldB(buf, j, 1); }
        if (kt + 1 < nt) stageB(buf ^ 1, 1, kt + 1);
        __builtin_amdgcn_s_barrier();
        __builtin_amdgcn_s_setprio(1);
        #pragma unroll
        for (int i = 0; i < 4; i++)
            #pragma unroll
            for (int j = 0; j < 2; j++) {
                acc[i][j] = MFMA16(af[i][0], bfr[j][0], acc[i][j], 0, 0, 0);
                acc[i][j] = MFMA16(af[i][1], bfr[j][1], acc[i][j], 0, 0, 0);
            }
        __builtin_amdgcn_s_setprio(0);
        __builtin_amdgcn_s_barrier();
        // ---- phase 1: i0-3 x j2-3 (4 ds_reads)
        #pragma unroll
        for (int j = 2; j < 4; j++) { bfr[j][0] = ldB(buf, j, 0); bfr[j][1] = ldB(buf, j, 1); }
        __builtin_amdgcn_s_barrier();
        __builtin_amdgcn_s_setprio(1);
        #pragma unroll
        for (int i = 0; i < 4; i++)
            #pragma unroll
            for (int j = 0; j < 2; j++) {
                acc[i][2 + j] = MFMA16(af[i][0], bfr[2 + j][0], acc[i][2 + j], 0, 0, 0);
                acc[i][2 + j] = MFMA16(af[i][1], bfr[2 + j][1], acc[i][2 + j], 0, 0, 0);
            }
        __builtin_amdgcn_s_setprio(0);
        __builtin_amdgcn_s_barrier();
        // ---- phase 2: i4-7 x j0-1 (8 ds_reads, af reused); stage B0(t+2) -> buf
        #pragma unroll
        for (int i = 0; i < 4; i++) { af[i][0] = ldA(buf, 4 + i, 0); af[i][1] = ldA(buf, 4 + i, 1); }
        if (kt + 2 < nt) stageB(buf, 0, kt + 2);
        __builtin_amdgcn_s_barrier();
        __builtin_amdgcn_s_setprio(1);
        #pragma unroll
        for (int i = 0; i < 4; i++)
            #pragma unroll
            for (int j = 0; j < 2; j++) {
                acc[4 + i][j] = MFMA16(af[i][0], bfr[j][0], acc[4 + i][j], 0, 0, 0);
                acc[4 + i][j] = MFMA16(af[i][1], bfr[j][1], acc[4 + i][j], 0, 0, 0);
            }
        __builtin_amdgcn_s_setprio(0);
        __builtin_amdgcn_s_barrier();
        // ---- phase 3: i4-7 x j2-3 (0 ds_reads); stage A0,A1(t+2) -> buf
        if (kt + 2 < nt) { stageA(buf, 0, kt + 2); stageA(buf, 1, kt + 2); }
        __builtin_amdgcn_s_barrier();
        __builtin_amdgcn_s_setprio(1);
        #pragma unroll
        for (int i = 0; i < 4; i++)
            #pragma unroll
            for (int j = 0; j < 2; j++) {
                acc[4 + i][2 + j] = MFMA16(af[i][0], bfr[2 + j][0], acc[4 + i][2 + j], 0, 0, 0);
                acc[4 + i][2 + j] = MFMA16(af[i][1], bfr[2 + j][1], acc[4 + i][2 + j], 0, 0, 0);
            }
        __builtin_amdgcn_s_setprio(0);
        if (kt < nt - 2) asm volatile("s_waitcnt vmcnt(6)" ::: "memory");
        else             asm volatile("s_waitcnt vmcnt(0)" ::: "memory");
        __builtin_amdgcn_s_barrier();
    };
    for (int kt = 0; kt < nt; kt += 2) { tile(kt, 0); tile(kt + 1, 1); }

    // epilogue: C/D layout col=lane&15, row=(lane>>4)*4+q  (m89-verified)
    float bv[4];
    #pragma unroll
    for (int j = 0; j < 4; j++)
        bv[j] = bias[m0 + wn * 64 + j * 16 + lrow];
    #pragma unroll
    for (int i = 0; i < 8; i++) {
        const int srow0 = n0 + wm * 128 + i * 16 + kg * 4;
        #pragma unroll
        for (int j = 0; j < 4; j++) {
            const int col = m0 + wn * 64 + j * 16 + lrow;
            #pragma unroll
            for (int q = 0; q < 4; q++) {
                if (srow0 + q < cnt) {
                    float x = acc[i][j][q] + bv[j];
                    C[(size_t)(srow0 + q) * M + col] = f2b(fmaxf(x, 0.f));
                }
            }
        }
    }
}

template<int KT>
__global__ __launch_bounds__(512, 2) void gemm256(
    const unsigned short* __restrict__ A, const unsigned short* __restrict__ BT,
    const float* __restrict__ bias, unsigned short* __restrict__ C,
    int M, const int* __restrict__ rowlist, const int* __restrict__ cntp) {
    extern __shared__ char lds_[];
    gemm_core<KT>(A, BT, bias, C, M, rowlist, cntp, blockIdx.x, lds_);
}

// packed: bids [0,256) = G2 (K=HID);  bids [256,512) = G1 (K=IN_DIM)
__global__ __launch_bounds__(512, 2) void gemm256_dual(
    const unsigned short* __restrict__ A2, const unsigned short* __restrict__ BT2,
    const float* __restrict__ bias2, unsigned short* __restrict__ C2,
    const int* __restrict__ cnt2,
    const unsigned short* __restrict__ A1, const unsigned short* __restrict__ BT1,
    const float* __restrict__ bias1, unsigned short* __restrict__ C1,
    const int* __restrict__ rowlist1, const int* __restrict__ cnt1) {
    extern __shared__ char lds_[];
    const int bid = blockIdx.x;
    if (bid < 256) {
        gemm_core<HID>(A2, BT2, bias2, C2, HID, nullptr, cnt2, bid, lds_);
    } else {
        gemm_core<IN_DIM>(A1, BT1, bias1, C1, HID, rowlist1, cnt1, bid - 256, lds_);
    }
}

// packed: two G1 jobs (both K=IN_DIM, shared A)
__global__ __launch_bounds__(512, 2) void gemm256_dual_g1g1(
    const unsigned short* __restrict__ A,
    const unsigned short* __restrict__ BTa, const float* __restrict__ biasa,
    unsigned short* __restrict__ Ca, const int* __restrict__ rla, const int* __restrict__ cnta,
    const unsigned short* __restrict__ BTb, const float* __restrict__ biasb,
    unsigned short* __restrict__ Cb, const int* __restrict__ rlb, const int* __restrict__ cntb) {
    extern __shared__ char lds_[];
    const int bid = blockIdx.x;
    if (bid < 256) {
        gemm_core<IN_DIM>(A, BTa, biasa, Ca, HID, rla, cnta, bid, lds_);
    } else {
        gemm_core<IN_DIM>(A, BTb, biasb, Cb, HID, rlb, cntb, bid - 256, lds_);
    }
}

// packed: two G2 jobs (both K=HID)
__global__ __launch_bounds__(512, 2) void gemm256_dual_g2g2(
    const unsigned short* __restrict__ Aa, const unsigned short* __restrict__ BTa,
    const float* __restrict__ biasa, unsigned short* __restrict__ Ca, const int* __restrict__ cnta,
    const unsigned short* __restrict__ Ab, const unsigned short* __restrict__ BTb,
    const float* __restrict__ biasb, unsigned short* __restrict__ Cb, const int* __restrict__ cntb) {
    extern __shared__ char lds_[];
    const int bid = blockIdx.x;
    if (bid < 256) {
        gemm_core<HID>(Aa, BTa, biasa, Ca, HID, nullptr, cnta, bid, lds_);
    } else {
        gemm_core<HID>(Ab, BTb, biasb, Cb, HID, nullptr, cntb, bid - 256, lds_);
    }
}

// ---------------- Gram-Schmidt + gather: one wave per sample (compact obf via pos) ------------
__global__ __launch_bounds__(256, 1) void gs_kernel(
    const unsigned short* __restrict__ eo, const float* __restrict__ gval,
    const int* __restrict__ gidx, const int* __restrict__ pos,
    float* __restrict__ dout) {
    const int t = threadIdx.x, wave = t >> 6, lane = t & 63;
    const int n = blockIdx.x * 4 + wave;
    const int idx = gidx[n];
    const float g = gval[n];

    float v[32], b0[32], b1[32], b2[32];

    auto loadv = [&](float* dst, int e) {
        const size_t row = pos[(size_t)e * N_SAMP + n];
        const unsigned short* p = eo + ((size_t)e * N_SAMP + row) * HID + lane * 8;
        #pragma unroll
        for (int c = 0; c < 4; c++) {
            uint4 u = *(const uint4*)(p + c * 512);
            const unsigned short* us = (const unsigned short*)&u;
            #pragma unroll
            for (int j = 0; j < 8; j++) dst[c * 8 + j] = b2f(us[j]);
        }
    };
    auto wdot = [&](const float* x, const float* y) -> float {
        float s = 0.f;
        #pragma unroll
        for (int k = 0; k < 32; k++) s += x[k] * y[k];
        #pragma unroll
        for (int o = 32; o; o >>= 1) s += __shfl_xor(s, o);
        return s;
    };
    auto storev = [&](const float* b) {
        float* o = dout + (size_t)n * HID + lane * 8;
        #pragma unroll
        for (int c = 0; c < 4; c++) {
            float4 x0, x1;
            x0.x = g * b[c * 8 + 0]; x0.y = g * b[c * 8 + 1];
            x0.z = g * b[c * 8 + 2]; x0.w = g * b[c * 8 + 3];
            x1.x = g * b[c * 8 + 4]; x1.y = g * b[c * 8 + 5];
            x1.z = g * b[c * 8 + 6]; x1.w = g * b[c * 8 + 7];
            *(float4*)(o + c * 512) = x0;
            *(float4*)(o + c * 512 + 4) = x1;
        }
    };

    loadv(v, 0);
    float inv = 1.f / sqrtf(wdot(v, v));
    #pragma unroll
    for (int k = 0; k < 32; k++) b0[k] = v[k] * inv;
    if (idx == 0) { storev(b0); return; }
    loadv(v, 1);
    {
        float cc0 = wdot(v, b0);
        #pragma unroll
        for (int k = 0; k < 32; k++) v[k] -= cc0 * b0[k];
        inv = 1.f / sqrtf(wdot(v, v));
        #pragma unroll
        for (int k = 0; k < 32; k++) b1[k] = v[k] * inv;
    }
    if (idx == 1) { storev(b1); return; }
    loadv(v, 2);
    {
        float cc0 = wdot(v, b0);
        float cc1 = wdot(v, b1);
        #pragma unroll
        for (int k = 0; k < 32; k++) v[k] -= cc0 * b0[k] + cc1 * b1[k];
        inv = 1.f / sqrtf(wdot(v, v));
        #pragma unroll
        for (int k = 0; k < 32; k++) b2[k] = v[k] * inv;
    }
    if (idx == 2) { storev(b2); return; }
    loadv(v, 3);
    {
        float cc0 = wdot(v, b0);
        float cc1 = wdot(v, b1);
        float cc2 = wdot(v, b2);
        #pragma unroll
        for (int k = 0; k < 32; k++) v[k] -= cc0 * b0[k] + cc1 * b1[k] + cc2 * b2[k];
        inv = 1.f / sqrtf(wdot(v, v));
        #pragma unroll
        for (int k = 0; k < 32; k++) v[k] *= inv;
    }
    storev(v);
}

extern "C" void kernel_launch(void* const* d_in, const int* in_sizes, int n_in,
                              void* d_out, int out_size, void* d_ws, size_t ws_size,
                              hipStream_t stream) {
    const float* bb   = (const float*)d_in[0];
    const int*   task = (const int*)d_in[1];
    const float* temb = (const float*)d_in[2];
    const float* rm   = (const float*)d_in[3];
    const float* W1   = (const float*)d_in[4];
    const float* b1   = (const float*)d_in[5];
    const float* W2   = (const float*)d_in[6];
    const float* b2   = (const float*)d_in[7];
    float* out = (float*)d_out;
    char* ws = (char*)d_ws;

    const size_t lds_bytes = 131072;
    const size_t W1S = (size_t)IN_DIM * HID;   // W1T expert stride (elements)
    const size_t W2S = (size_t)HID * HID;      // W2T expert stride (elements)
    const size_t NEED_C = 251986176;           // plan C: fully batched transposes
    const size_t NEED_B = 243597376;           // plan B: proven bound (r10/r11)

    if (ws_size >= NEED_B) {
        const bool planC = (ws_size >= NEED_C);
        // Shared core layout (both plans):
        unsigned short* obf  = (unsigned short*)(ws + 0);           // 128 MB [E][N][HID]
        unsigned short* h0   = (unsigned short*)(ws + 33554432);    // = obf[1] slot
        unsigned short* h1   = (unsigned short*)(ws + 67108864);    // = obf[2] slot
        unsigned short* Abf  = (unsigned short*)(ws + 134217728);   // 16 MB (dead after D2)
        unsigned short* h2   = (unsigned short*)(ws + 150994944);   // 32 MB
        unsigned short* h3   = (unsigned short*)(ws + 184549376);   // 32 MB
        unsigned short* W1T  = (unsigned short*)(ws + 218103808);   // 16 MB: all 4 experts
        unsigned short* W2T  = (unsigned short*)(ws + 234881024);   // C: 16 MB (e0,e1); B: 8 MB single
        unsigned short* W2T23 = Abf;                                // W2T(2),(3) land in dead Abf
        const size_t smallOfs = planC ? 251658240u : 243269632u;
        float* gv   = (float*)(ws + smallOfs);
        int*   gi   = (int*)(ws + smallOfs + 32768);
        int*   list = (int*)(ws + smallOfs + 65536);
        int*   pos  = (int*)(ws + smallOfs + 196608);
        int*   cnt  = (int*)(ws + smallOfs + 327680);

        conv_bf16<<<(N_SAMP * IN_DIM) / 1024, 256, 0, stream>>>(bb, Abf, N_SAMP * IN_DIM);
        router_kernel<<<N_SAMP / 4, 256, 0, stream>>>(bb, task, temb, rm, gv, gi,
                                                      out + (size_t)N_SAMP * HID);
        compact_kernel<<<NE, 256, 0, stream>>>(gi, list, pos, cnt);

        // W1 transposes: all 4 experts in ONE dispatch
        transpose_conv<<<dim3(IN_DIM / 64, HID / 64, NE), 256, 0, stream>>>(
            W1, W1T, IN_DIM, HID, W1S, W1S);
        // W2 transposes (pre-D2 part)
        if (planC) {
            transpose_conv<<<dim3(HID / 64, HID / 64, 2), 256, 0, stream>>>(
                W2, W2T, HID, HID, W2S, W2S);                   // e0 -> W2T, e1 -> W2T+W2S
        } else {
            transpose_conv<<<dim3(HID / 64, HID / 64, 1), 256, 0, stream>>>(
                W2, W2T, HID, HID, 0, 0);                       // e0 -> W2T (single buffer)
        }

        // D0: [G1(0)->h0 | G1(1)->h1]
        gemm256_dual_g1g1<<<512, 512, lds_bytes, stream>>>(
            Abf, W1T, b1, h0, list, cnt,
            W1T + W1S, b1 + HID, h1, list + N_SAMP, cnt + 1);

        // D1: [G2(0): h0 -> obf0 | G1(2) -> h2]
        gemm256_dual<<<512, 512, lds_bytes, stream>>>(
            h0, W2T, b2, obf, cnt,
            Abf, W1T + 2 * W1S, b1 + 2 * HID, h2, list + (size_t)2 * N_SAMP, cnt + 2);

        if (!planC) {
            // plan B: stage W2T(1) into the single buffer (after D1 finished reading e0)
            transpose_conv<<<dim3(HID / 64, HID / 64, 1), 256, 0, stream>>>(
                W2 + W2S, W2T, HID, HID, 0, 0);
        }
        const unsigned short* W2T1 = planC ? (W2T + W2S) : W2T;

        // D2: [G2(1): h1 -> obf1 | G1(3) -> h3]
        gemm256_dual<<<512, 512, lds_bytes, stream>>>(
            h1, W2T1, b2 + HID, obf + (size_t)1 * N_SAMP * HID, cnt + 1,
            Abf, W1T + 3 * W1S, b1 + 3 * HID, h3, list + (size_t)3 * N_SAMP, cnt + 3);

        // W2T(2),(3) -> dead Abf region (Abf's last read was G1(3) in D2)
        transpose_conv<<<dim3(HID / 64, HID / 64, 2), 256, 0, stream>>>(
            W2 + 2 * W2S, W2T23, HID, HID, W2S, W2S);

        // D3: [G2(2): h2 -> obf2 | G2(3): h3 -> obf3]
        gemm256_dual_g2g2<<<512, 512, lds_bytes, stream>>>(
            h2, W2T23, b2 + 2 * HID, obf + (size_t)2 * N_SAMP * HID, cnt + 2,
            h3, W2T23 + W2S, b2 + 3 * HID, obf + (size_t)3 * N_SAMP * HID, cnt + 3);

        gs_kernel<<<N_SAMP / 4, 256, 0, stream>>>(obf, gv, gi, pos, out);
    } else {
        // ===== fallback: round-9 structure, ~197.5 MB (proven) =====
        unsigned short* obf  = (unsigned short*)(ws + 0);
        unsigned short* Abf  = (unsigned short*)(ws + 134217728);
        unsigned short* hbfA = (unsigned short*)(ws + 150994944);
        unsigned short* W1T  = (unsigned short*)(ws + 184549376);
        unsigned short* W2T  = (unsigned short*)(ws + 188743680);
        float*          gv   = (float*)(ws + 197132288);
        int*            gi   = (int*)(ws + 197165056);
        int*            list = (int*)(ws + 197197824);
        int*            pos  = (int*)(ws + 197328896);
        int*            cnt  = (int*)(ws + 197459968);
        unsigned short* hbfB = obf + (size_t)3 * N_SAMP * HID;
        auto hbf = [&](int e) { return (e & 1) ? hbfA : hbfB; };

        conv_bf16<<<(N_SAMP * IN_DIM) / 1024, 256, 0, stream>>>(bb, Abf, N_SAMP * IN_DIM);
        router_kernel<<<N_SAMP / 4, 256, 0, stream>>>(bb, task, temb, rm, gv, gi,
                                                      out + (size_t)N_SAMP * HID);
        compact_kernel<<<NE, 256, 0, stream>>>(gi, list, pos, cnt);

        transpose_conv<<<dim3(IN_DIM / 64, HID / 64, 1), 256, 0, stream>>>(
            W1, W1T, IN_DIM, HID, 0, 0);
        gemm256<IN_DIM><<<256, 512, lds_bytes, stream>>>(
            Abf, W1T, b1, hbf(0), HID, list, cnt);

        for (int e = 0; e < 3; ++e) {
            transpose_conv<<<dim3(HID / 64, HID / 64, 1), 256, 0, stream>>>(
                W2 + (size_t)e * W2S, W2T, HID, HID, 0, 0);
            transpose_conv<<<dim3(IN_DIM / 64, HID / 64, 1), 256, 0, stream>>>(
                W1 + (size_t)(e + 1) * W1S, W1T, IN_DIM, HID, 0, 0);
            gemm256_dual<<<512, 512, lds_bytes, stream>>>(
                hbf(e), W2T, b2 + (size_t)e * HID, obf + (size_t)e * N_SAMP * HID, cnt + e,
                Abf, W1T, b1 + (size_t)(e + 1) * HID, hbf(e + 1),
                list + (size_t)(e + 1) * N_SAMP, cnt + e + 1);
        }

        transpose_conv<<<dim3(HID / 64, HID / 64, 1), 256, 0, stream>>>(
            W2 + (size_t)3 * W2S, W2T, HID, HID, 0, 0);
        gemm256<HID><<<256, 512, lds_bytes, stream>>>(
            hbf(3), W2T, b2 + (size_t)3 * HID, obf + (size_t)3 * N_SAMP * HID, HID,
            nullptr, cnt + 3);

        gs_kernel<<<N_SAMP / 4, 256, 0, stream>>>(obf, gv, gi, pos, out);
    }
}